// Round 2
// baseline (11227.943 us; speedup 1.0000x reference)
//
#include <hip/hip_runtime.h>
#include <hip/hip_bf16.h>
#include <math.h>

#define B 2
#define L 2048
#define DM 768
#define NH 12
#define DH 64
#define DFF 2304
#define M_TOK (B * L) // 4096

__device__ __forceinline__ float waveSum(float v) {
#pragma unroll
  for (int o = 32; o > 0; o >>= 1) v += __shfl_down(v, o, 64);
  return v;
}
__device__ __forceinline__ float waveMax(float v) {
#pragma unroll
  for (int o = 32; o > 0; o >>= 1) v = fmaxf(v, __shfl_down(v, o, 64));
  return v;
}
__device__ __forceinline__ float waveAllSum(float v) {
#pragma unroll
  for (int o = 32; o > 0; o >>= 1) v += __shfl_xor(v, o, 64);
  return v;
}

// ---------- RMSNorm: one block (256 thr) per row of 768 ----------
__global__ __launch_bounds__(256) void k_rmsnorm(const float* __restrict__ in,
                                                 const float* __restrict__ scale,
                                                 float* __restrict__ out) {
  int row = blockIdx.x;
  int t = threadIdx.x;
  const float* r = in + (size_t)row * DM;
  float x0 = r[t], x1 = r[t + 256], x2 = r[t + 512];
  float ss = x0 * x0 + x1 * x1 + x2 * x2;
  ss = waveSum(ss);
  __shared__ float red[4];
  int w = t >> 6, ln = t & 63;
  if (ln == 0) red[w] = ss;
  __syncthreads();
  float tot = red[0] + red[1] + red[2] + red[3];
  float g = rsqrtf(tot / (float)DM + 1e-6f);
  float* o = out + (size_t)row * DM;
  o[t] = x0 * g * scale[t];
  o[t + 256] = x1 * g * scale[t + 256];
  o[t + 512] = x2 * g * scale[t + 512];
}

// ---------- generic tiled GEMM: C(MxN) = A(MxK) @ W(NxK)^T (+res) ----------
#define BM 64
#define BN 64
#define BK 16
__global__ __launch_bounds__(256) void k_gemm_nt(const float* __restrict__ A,
                                                 const float* __restrict__ W,
                                                 float* __restrict__ C,
                                                 const float* __restrict__ res,
                                                 int M, int N, int K) {
  __shared__ float As[BK][BM + 4];
  __shared__ float Ws[BK][BN + 4];
  int n0 = blockIdx.x * BN, m0 = blockIdx.y * BM;
  int t = threadIdx.x;
  int tx = t & 15, ty = t >> 4;
  float acc[4][4] = {};
  for (int k0 = 0; k0 < K; k0 += BK) {
#pragma unroll
    for (int i = 0; i < 4; i++) {
      int idx = t + i * 256;
      int m = idx >> 4, kk = idx & 15;
      As[kk][m] = A[(size_t)(m0 + m) * K + k0 + kk];
      Ws[kk][m] = W[(size_t)(n0 + m) * K + k0 + kk];
    }
    __syncthreads();
#pragma unroll
    for (int kk = 0; kk < BK; kk++) {
      float a[4], b[4];
#pragma unroll
      for (int i = 0; i < 4; i++) a[i] = As[kk][ty * 4 + i];
#pragma unroll
      for (int j = 0; j < 4; j++) b[j] = Ws[kk][tx * 4 + j];
#pragma unroll
      for (int i = 0; i < 4; i++)
#pragma unroll
        for (int j = 0; j < 4; j++) acc[i][j] += a[i] * b[j];
    }
    __syncthreads();
  }
#pragma unroll
  for (int i = 0; i < 4; i++) {
    int m = m0 + ty * 4 + i;
#pragma unroll
    for (int j = 0; j < 4; j++) {
      int n = n0 + tx * 4 + j;
      float c = acc[i][j];
      if (res) c += res[(size_t)m * N + n];
      C[(size_t)m * N + n] = c;
    }
  }
}

// ---------- cos-scale + RoPE (+transpose to (B,H,L,DH)); one wave per (b,h,l) ----------
__global__ __launch_bounds__(256) void k_rope_cs(const float* __restrict__ in, int in_stride,
                                                 int in_off, const float* __restrict__ pos,
                                                 const float* __restrict__ scale,
                                                 float* __restrict__ out, int do_rope) {
  int item = blockIdx.x * 4 + (threadIdx.x >> 6); // item = (b*NH + h)*L + l
  int lane = threadIdx.x & 63;
  int l = item % L;
  int bh = item / L;
  int h = bh % NH;
  int b = bh / NH;
  float x = in[(size_t)(b * L + l) * in_stride + in_off + h * DH + lane];
  float o;
  if (do_rope) {
    float ss = waveAllSum(x * x);
    float s = sqrtf(scale[h]);
    x *= s * rsqrtf(ss + 1e-6f);
    int j = lane < 24 ? lane : (lane < 48 ? lane - 24 : 0);
    int partner = lane < 24 ? lane + 24 : (lane < 48 ? lane - 24 : lane);
    float other = __shfl(x, partner, 64);
    if (lane < 48) {
      int c = j >> 3, f = j & 7;
      // ROPE_FREQS[h][f] = pi * 10^((f*12+h)/96)
      float fr = __expf(1.14472988584940017f +
                        (float)(f * 12 + h) * (2.30258509299404568f / 96.0f));
      float th = pos[(size_t)(b * L + l) * 3 + c] * fr;
      float st, ct;
      sincosf(th, &st, &ct);
      o = (lane < 24) ? (x * ct - other * st) : (x * ct + other * st);
    } else {
      o = x;
    }
  } else {
    o = x;
  }
  out[(size_t)item * DH + lane] = o;
}

// ---------- attention: one block (256 thr) per (b,h,q-row); full-row softmax ----------
__global__ __launch_bounds__(256) void k_attn(const float* __restrict__ Q,
                                              const float* __restrict__ Kt,
                                              const float* __restrict__ V,
                                              float* __restrict__ O) {
  __shared__ float sc[L]; // 8 KB
  __shared__ __align__(16) float qv[DH];
  __shared__ __align__(16) float op[4][DH];
  __shared__ float red[4];
  int qi = blockIdx.x % L;
  int bh = blockIdx.x / L;
  int t = threadIdx.x;
  if (t < DH) qv[t] = Q[(size_t)(bh * L + qi) * DH + t];
  __syncthreads();
  const float* kbase = Kt + (size_t)bh * L * DH;
  float lmax = -1e30f;
#pragma unroll
  for (int tt = 0; tt < 8; tt++) {
    int j = tt * 256 + t;
    const float4* kr = (const float4*)(kbase + (size_t)j * DH);
    const float4* q4 = (const float4*)qv;
    float s = 0.f;
#pragma unroll
    for (int d4 = 0; d4 < 16; d4++) {
      float4 kv4 = kr[d4];
      float4 qq = q4[d4];
      s += kv4.x * qq.x + kv4.y * qq.y + kv4.z * qq.z + kv4.w * qq.w;
    }
    sc[j] = s;
    lmax = fmaxf(lmax, s);
  }
  lmax = waveMax(lmax);
  int w = t >> 6, ln = t & 63;
  if (ln == 0) red[w] = lmax;
  __syncthreads();
  float m = fmaxf(fmaxf(red[0], red[1]), fmaxf(red[2], red[3]));
  __syncthreads();
  float lsum = 0.f;
#pragma unroll
  for (int tt = 0; tt < 8; tt++) {
    int j = tt * 256 + t;
    float e = __expf(sc[j] - m);
    sc[j] = e;
    lsum += e;
  }
  lsum = waveSum(lsum);
  if (ln == 0) red[w] = lsum;
  __syncthreads();
  float ssum = red[0] + red[1] + red[2] + red[3];
  int c = t >> 6, d = t & 63;
  const float* vbase = V + (size_t)bh * L * DH + d;
  float acc = 0.f;
  int j0 = c * 512;
  for (int j = j0; j < j0 + 512; j++) acc += sc[j] * vbase[(size_t)j * DH];
  op[c][d] = acc;
  __syncthreads();
  if (t < DH) {
    float o = (op[0][t] + op[1][t] + op[2][t] + op[3][t]) / ssum;
    int b = bh / NH, h = bh % NH;
    O[(size_t)((b * L + qi) * NH + h) * DH + t] = o;
  }
}

// ---------- SwiGLU: out[m,j] = a * silu(g) ----------
__global__ void k_ffact(const float* __restrict__ U, float* __restrict__ Out) {
  int idx = blockIdx.x * blockDim.x + threadIdx.x;
  int total = M_TOK * DFF;
  if (idx >= total) return;
  int mrow = idx / DFF, jj = idx % DFF;
  float a = U[(size_t)mrow * (2 * DFF) + jj];
  float g = U[(size_t)mrow * (2 * DFF) + DFF + jj];
  Out[idx] = a * g / (1.f + __expf(-g));
}

extern "C" void kernel_launch(void* const* d_in, const int* in_sizes, int n_in,
                              void* d_out, int out_size, void* d_ws, size_t ws_size,
                              hipStream_t stream) {
  const float* x = (const float*)d_in[0];
  const float* pos = (const float*)d_in[1];
  const float* x_cross = (const float*)d_in[2];
  const float* pos_cross = (const float*)d_in[3];
  const float* sa_norm_scale = (const float*)d_in[4];
  const float* sa_wqkv = (const float*)d_in[5];
  const float* sa_scale = (const float*)d_in[6];
  const float* sa_wout = (const float*)d_in[7];
  const float* ca_norm_scale = (const float*)d_in[8];
  const float* ca_norm_cross_scale = (const float*)d_in[9];
  const float* ca_wq = (const float*)d_in[10];
  const float* ca_wkv = (const float*)d_in[11];
  const float* ca_scale = (const float*)d_in[12];
  const float* ca_wout = (const float*)d_in[13];
  const float* ff_norm_scale = (const float*)d_in[14];
  const float* ff_wup = (const float*)d_in[15];
  const float* ff_wdown = (const float*)d_in[16];
  float* out = (float*)d_out;

  float* ws = (float*)d_ws;
  const size_t S = (size_t)M_TOK * DM; // 3,145,728 floats
  float* xbuf = ws;            // running residual (f32)
  float* hbuf = ws + S;        // normed activations
  float* hcbuf = ws + 2 * S;   // normed cross activations
  float* qbuf = ws + 3 * S;    // (B,H,L,DH)
  float* kbuf = ws + 4 * S;
  float* vbuf = ws + 5 * S;
  float* obuf = ws + 6 * S;    // attn out (B,L,H,DH) / temp
  float* bigbuf = ws + 7 * S;  // 6*S: qkv / kv / ff-up
  float* ffact = qbuf;         // 3*S, aliases q/k/v after attention done

  const int ropeGrid = B * NH * L / 4;

  // ---- prologue: residual init + cross norm ----
  hipMemcpyAsync(xbuf, x, S * sizeof(float), hipMemcpyDeviceToDevice, stream);
  k_rmsnorm<<<M_TOK, 256, 0, stream>>>(x_cross, ca_norm_cross_scale, hcbuf);

  // ---- self attention ----
  k_rmsnorm<<<M_TOK, 256, 0, stream>>>(xbuf, sa_norm_scale, hbuf);
  k_gemm_nt<<<dim3(3 * DM / BN, M_TOK / BM), 256, 0, stream>>>(
      hbuf, sa_wqkv, bigbuf, nullptr, M_TOK, 3 * DM, DM);
  k_rope_cs<<<ropeGrid, 256, 0, stream>>>(bigbuf, 3 * DM, 0, pos, sa_scale, qbuf, 1);
  k_rope_cs<<<ropeGrid, 256, 0, stream>>>(bigbuf, 3 * DM, DM, pos, sa_scale, kbuf, 1);
  k_rope_cs<<<ropeGrid, 256, 0, stream>>>(bigbuf, 3 * DM, 2 * DM, nullptr, nullptr, vbuf, 0);
  k_attn<<<B * NH * L, 256, 0, stream>>>(qbuf, kbuf, vbuf, obuf);
  k_gemm_nt<<<dim3(DM / BN, M_TOK / BM), 256, 0, stream>>>(
      obuf, sa_wout, xbuf, xbuf, M_TOK, DM, DM);

  // ---- cross attention ----
  k_rmsnorm<<<M_TOK, 256, 0, stream>>>(xbuf, ca_norm_scale, hbuf);
  k_gemm_nt<<<dim3(DM / BN, M_TOK / BM), 256, 0, stream>>>(
      hbuf, ca_wq, obuf, nullptr, M_TOK, DM, DM);
  k_gemm_nt<<<dim3(2 * DM / BN, M_TOK / BM), 256, 0, stream>>>(
      hcbuf, ca_wkv, bigbuf, nullptr, M_TOK, 2 * DM, DM);
  k_rope_cs<<<ropeGrid, 256, 0, stream>>>(obuf, DM, 0, pos, ca_scale, qbuf, 1);
  k_rope_cs<<<ropeGrid, 256, 0, stream>>>(bigbuf, 2 * DM, 0, pos_cross, ca_scale, kbuf, 1);
  k_rope_cs<<<ropeGrid, 256, 0, stream>>>(bigbuf, 2 * DM, DM, nullptr, nullptr, vbuf, 0);
  k_attn<<<B * NH * L, 256, 0, stream>>>(qbuf, kbuf, vbuf, obuf);
  k_gemm_nt<<<dim3(DM / BN, M_TOK / BM), 256, 0, stream>>>(
      obuf, ca_wout, xbuf, xbuf, M_TOK, DM, DM);

  // ---- feed-forward ----
  k_rmsnorm<<<M_TOK, 256, 0, stream>>>(xbuf, ff_norm_scale, hbuf);
  k_gemm_nt<<<dim3(2 * DFF / BN, M_TOK / BM), 256, 0, stream>>>(
      hbuf, ff_wup, bigbuf, nullptr, M_TOK, 2 * DFF, DM);
  const int nFF = M_TOK * DFF;
  k_ffact<<<(nFF + 255) / 256, 256, 0, stream>>>(bigbuf, ffact);
  k_gemm_nt<<<dim3(DM / BN, M_TOK / BM), 256, 0, stream>>>(
      ffact, ff_wdown, out, xbuf, M_TOK, DM, DFF);
}

// Round 3
// 2205.000 us; speedup vs baseline: 5.0920x; 5.0920x over previous
//
#include <hip/hip_runtime.h>
#include <hip/hip_bf16.h>
#include <math.h>

#define B 2
#define L 2048
#define DM 768
#define NH 12
#define DH 64
#define DFF 2304
#define M_TOK (B * L) // 4096

__device__ __forceinline__ float waveSum(float v) {
#pragma unroll
  for (int o = 32; o > 0; o >>= 1) v += __shfl_down(v, o, 64);
  return v;
}

// ---------- RMSNorm: one block (256 thr) per row of 768 ----------
__global__ __launch_bounds__(256) void k_rmsnorm(const float* __restrict__ in,
                                                 const float* __restrict__ scale,
                                                 float* __restrict__ out) {
  int row = blockIdx.x;
  int t = threadIdx.x;
  const float* r = in + (size_t)row * DM;
  float x0 = r[t], x1 = r[t + 256], x2 = r[t + 512];
  float ss = x0 * x0 + x1 * x1 + x2 * x2;
  ss = waveSum(ss);
  __shared__ float red[4];
  int w = t >> 6, ln = t & 63;
  if (ln == 0) red[w] = ss;
  __syncthreads();
  float tot = red[0] + red[1] + red[2] + red[3];
  float g = rsqrtf(tot / (float)DM + 1e-6f);
  float* o = out + (size_t)row * DM;
  o[t] = x0 * g * scale[t];
  o[t + 256] = x1 * g * scale[t + 256];
  o[t + 512] = x2 * g * scale[t + 512];
}

// ---------- generic tiled GEMM: C(MxN) = A(MxK) @ W(NxK)^T (+res) ----------
#define BM 64
#define BN 64
#define BK 16
__global__ __launch_bounds__(256) void k_gemm_nt(const float* __restrict__ A,
                                                 const float* __restrict__ W,
                                                 float* __restrict__ C,
                                                 const float* __restrict__ res,
                                                 int M, int N, int K) {
  __shared__ float As[BK][BM + 4];
  __shared__ float Ws[BK][BN + 4];
  int n0 = blockIdx.x * BN, m0 = blockIdx.y * BM;
  int t = threadIdx.x;
  int tx = t & 15, ty = t >> 4;
  float acc[4][4] = {};
  for (int k0 = 0; k0 < K; k0 += BK) {
#pragma unroll
    for (int i = 0; i < 4; i++) {
      int idx = t + i * 256;
      int m = idx >> 4, kk = idx & 15;
      As[kk][m] = A[(size_t)(m0 + m) * K + k0 + kk];
      Ws[kk][m] = W[(size_t)(n0 + m) * K + k0 + kk];
    }
    __syncthreads();
#pragma unroll
    for (int kk = 0; kk < BK; kk++) {
      float a[4], b[4];
#pragma unroll
      for (int i = 0; i < 4; i++) a[i] = As[kk][ty * 4 + i];
#pragma unroll
      for (int j = 0; j < 4; j++) b[j] = Ws[kk][tx * 4 + j];
#pragma unroll
      for (int i = 0; i < 4; i++)
#pragma unroll
        for (int j = 0; j < 4; j++) acc[i][j] += a[i] * b[j];
    }
    __syncthreads();
  }
#pragma unroll
  for (int i = 0; i < 4; i++) {
    int m = m0 + ty * 4 + i;
#pragma unroll
    for (int j = 0; j < 4; j++) {
      int n = n0 + tx * 4 + j;
      float c = acc[i][j];
      if (res) c += res[(size_t)m * N + n];
      C[(size_t)m * N + n] = c;
    }
  }
}

// ---------- cos-scale + RoPE; one wave per (b,h,l) ----------
// transpose=1: out layout (bh, d, L)  [for Q,K feeding tiled attention]
// transpose=0: out layout (bh, L, d)  [for V]
__global__ __launch_bounds__(256) void k_rope_cs(const float* __restrict__ in, int in_stride,
                                                 int in_off, const float* __restrict__ pos,
                                                 const float* __restrict__ scale,
                                                 float* __restrict__ out, int do_rope,
                                                 int transpose) {
  int item = blockIdx.x * 4 + (threadIdx.x >> 6); // item = (b*NH + h)*L + l
  int lane = threadIdx.x & 63;
  int l = item % L;
  int bh = item / L;
  int h = bh % NH;
  int b = bh / NH;
  float x = in[(size_t)(b * L + l) * in_stride + in_off + h * DH + lane];
  float o;
  if (do_rope) {
    float ss = x * x;
#pragma unroll
    for (int m = 32; m > 0; m >>= 1) ss += __shfl_xor(ss, m, 64);
    float s = sqrtf(scale[h]);
    x *= s * rsqrtf(ss + 1e-6f);
    int j = lane < 24 ? lane : (lane < 48 ? lane - 24 : 0);
    int partner = lane < 24 ? lane + 24 : (lane < 48 ? lane - 24 : lane);
    float other = __shfl(x, partner, 64);
    if (lane < 48) {
      int c = j >> 3, f = j & 7;
      // ROPE_FREQS[h][f] = pi * 10^((f*12+h)/96)
      float fr = __expf(1.14472988584940017f +
                        (float)(f * 12 + h) * (2.30258509299404568f / 96.0f));
      float th = pos[(size_t)(b * L + l) * 3 + c] * fr;
      float st, ct;
      sincosf(th, &st, &ct);
      o = (lane < 24) ? (x * ct - other * st) : (x * ct + other * st);
    } else {
      o = x;
    }
  } else {
    o = x;
  }
  if (transpose)
    out[((size_t)bh * DH + lane) * L + l] = o;
  else
    out[(size_t)item * DH + lane] = o;
}

// ---------- tiled flash attention ----------
// Qt, Kt: (B*NH, DH, L) transposed; V: (B*NH, L, DH); O: (B, L, NH, DH)
// block = 256 thr handles 64 queries of one (b,h); loops over 32 key tiles of 64.
#define PADT 68
__global__ __launch_bounds__(256) void k_attn_tile(const float* __restrict__ Qt,
                                                   const float* __restrict__ Kt,
                                                   const float* __restrict__ V,
                                                   float* __restrict__ O) {
  __shared__ float Qs[DH][PADT];  // [d][q]
  __shared__ float KV[64][PADT];  // K phase: [d][k]; V phase: [k][d]
  __shared__ float St[64][PADT];  // [q][k]  (p-values)
  int qt = blockIdx.x & 31;       // L/64
  int bh = blockIdx.x >> 5;
  int t = threadIdx.x;
  int tx = t & 15, ty = t >> 4;   // 16x16 threads, 4x4 patches
  int r0 = t >> 4, c0 = t & 15;   // staging: row r0(+16*it), float4 col c0

  // ---- load Q tile (once) ----
  const float* qbase = Qt + ((size_t)bh * DH) * L + qt * 64;
#pragma unroll
  for (int it = 0; it < 4; it++) {
    int d = r0 + it * 16;
    *(float4*)&Qs[d][c0 * 4] = *(const float4*)&qbase[(size_t)d * L + c0 * 4];
  }

  float o[4][4] = {};
  float m_run[4], l_run[4];
#pragma unroll
  for (int i = 0; i < 4; i++) { m_run[i] = -1e30f; l_run[i] = 0.f; }

  const float* kbase = Kt + ((size_t)bh * DH) * L;
  const float* vbase = V + ((size_t)bh * L) * DH;

  for (int kt = 0; kt < 32; kt++) {
    int k0 = kt * 64;
    __syncthreads();  // prev PV done reading KV/St
    // ---- load K tile: KV[d][k] ----
#pragma unroll
    for (int it = 0; it < 4; it++) {
      int d = r0 + it * 16;
      *(float4*)&KV[d][c0 * 4] = *(const float4*)&kbase[(size_t)d * L + k0 + c0 * 4];
    }
    __syncthreads();
    // ---- S = Q K^T : s[i][j], q=4ty+i, k=4tx+j ----
    float s[4][4] = {};
#pragma unroll 8
    for (int d = 0; d < DH; d++) {
      float4 a = *(const float4*)&Qs[d][ty * 4];
      float4 b = *(const float4*)&KV[d][tx * 4];
      float av[4] = {a.x, a.y, a.z, a.w};
      float bv[4] = {b.x, b.y, b.z, b.w};
#pragma unroll
      for (int i = 0; i < 4; i++)
#pragma unroll
        for (int j = 0; j < 4; j++) s[i][j] += av[i] * bv[j];
    }
    __syncthreads();  // QK reads of KV done
    // ---- load V tile: KV[k][d] ----
#pragma unroll
    for (int it = 0; it < 4; it++) {
      int k = r0 + it * 16;
      *(float4*)&KV[k][c0 * 4] = *(const float4*)&vbase[(size_t)(k0 + k) * DH + c0 * 4];
    }
    // ---- online softmax (register state, replicated over tx lanes) ----
#pragma unroll
    for (int i = 0; i < 4; i++) {
      float rm = fmaxf(fmaxf(s[i][0], s[i][1]), fmaxf(s[i][2], s[i][3]));
#pragma unroll
      for (int msk = 1; msk < 16; msk <<= 1) rm = fmaxf(rm, __shfl_xor(rm, msk, 64));
      float mn = fmaxf(m_run[i], rm);
      float alpha = __expf(m_run[i] - mn);
      float p0 = __expf(s[i][0] - mn), p1 = __expf(s[i][1] - mn);
      float p2 = __expf(s[i][2] - mn), p3 = __expf(s[i][3] - mn);
      float rs = p0 + p1 + p2 + p3;
#pragma unroll
      for (int msk = 1; msk < 16; msk <<= 1) rs += __shfl_xor(rs, msk, 64);
      l_run[i] = l_run[i] * alpha + rs;
      m_run[i] = mn;
#pragma unroll
      for (int j = 0; j < 4; j++) o[i][j] *= alpha;
      float4 pv = {p0, p1, p2, p3};
      *(float4*)&St[ty * 4 + i][tx * 4] = pv;
    }
    __syncthreads();  // St + V tile visible
    // ---- O += P V ----
#pragma unroll 4
    for (int kk = 0; kk < 64; kk += 4) {
      float4 a0 = *(const float4*)&St[ty * 4 + 0][kk];
      float4 a1 = *(const float4*)&St[ty * 4 + 1][kk];
      float4 a2 = *(const float4*)&St[ty * 4 + 2][kk];
      float4 a3 = *(const float4*)&St[ty * 4 + 3][kk];
      float4 b0 = *(const float4*)&KV[kk + 0][tx * 4];
      float4 b1 = *(const float4*)&KV[kk + 1][tx * 4];
      float4 b2 = *(const float4*)&KV[kk + 2][tx * 4];
      float4 b3 = *(const float4*)&KV[kk + 3][tx * 4];
      float am[4][4] = {{a0.x, a0.y, a0.z, a0.w}, {a1.x, a1.y, a1.z, a1.w},
                        {a2.x, a2.y, a2.z, a2.w}, {a3.x, a3.y, a3.z, a3.w}};
      float bm[4][4] = {{b0.x, b0.y, b0.z, b0.w}, {b1.x, b1.y, b1.z, b1.w},
                        {b2.x, b2.y, b2.z, b2.w}, {b3.x, b3.y, b3.z, b3.w}};
#pragma unroll
      for (int c = 0; c < 4; c++)
#pragma unroll
        for (int i = 0; i < 4; i++)
#pragma unroll
          for (int j = 0; j < 4; j++) o[i][j] += am[i][c] * bm[c][j];
    }
  }
  // ---- epilogue: normalize + store (B,L,NH,DH) ----
  int b = bh / NH, h = bh % NH;
#pragma unroll
  for (int i = 0; i < 4; i++) {
    float inv = 1.f / l_run[i];
    int l = qt * 64 + ty * 4 + i;
    float4 ov = {o[i][0] * inv, o[i][1] * inv, o[i][2] * inv, o[i][3] * inv};
    *(float4*)&O[(((size_t)b * L + l) * NH + h) * DH + tx * 4] = ov;
  }
}

// ---------- SwiGLU: out[m,j] = a * silu(g) ----------
__global__ void k_ffact(const float* __restrict__ U, float* __restrict__ Out) {
  int idx = blockIdx.x * blockDim.x + threadIdx.x;
  int total = M_TOK * DFF;
  if (idx >= total) return;
  int mrow = idx / DFF, jj = idx % DFF;
  float a = U[(size_t)mrow * (2 * DFF) + jj];
  float g = U[(size_t)mrow * (2 * DFF) + DFF + jj];
  Out[idx] = a * g / (1.f + __expf(-g));
}

extern "C" void kernel_launch(void* const* d_in, const int* in_sizes, int n_in,
                              void* d_out, int out_size, void* d_ws, size_t ws_size,
                              hipStream_t stream) {
  const float* x = (const float*)d_in[0];
  const float* pos = (const float*)d_in[1];
  const float* x_cross = (const float*)d_in[2];
  const float* pos_cross = (const float*)d_in[3];
  const float* sa_norm_scale = (const float*)d_in[4];
  const float* sa_wqkv = (const float*)d_in[5];
  const float* sa_scale = (const float*)d_in[6];
  const float* sa_wout = (const float*)d_in[7];
  const float* ca_norm_scale = (const float*)d_in[8];
  const float* ca_norm_cross_scale = (const float*)d_in[9];
  const float* ca_wq = (const float*)d_in[10];
  const float* ca_wkv = (const float*)d_in[11];
  const float* ca_scale = (const float*)d_in[12];
  const float* ca_wout = (const float*)d_in[13];
  const float* ff_norm_scale = (const float*)d_in[14];
  const float* ff_wup = (const float*)d_in[15];
  const float* ff_wdown = (const float*)d_in[16];
  float* out = (float*)d_out;

  float* ws = (float*)d_ws;
  const size_t S = (size_t)M_TOK * DM; // 3,145,728 floats
  float* xbuf = ws;            // running residual (f32)
  float* hbuf = ws + S;        // normed activations
  float* hcbuf = ws + 2 * S;   // normed cross activations
  float* qbuf = ws + 3 * S;    // (BH, DH, L) transposed
  float* kbuf = ws + 4 * S;    // (BH, DH, L) transposed
  float* vbuf = ws + 5 * S;    // (BH, L, DH)
  float* obuf = ws + 6 * S;    // attn out (B,L,H,DH) / temp
  float* bigbuf = ws + 7 * S;  // 6*S: qkv / kv / ff-up
  float* ffact = qbuf;         // 3*S, aliases q/k/v after attention done

  const int ropeGrid = B * NH * L / 4;
  const int attnGrid = B * NH * (L / 64); // 768

  // ---- prologue: residual init + cross norm ----
  hipMemcpyAsync(xbuf, x, S * sizeof(float), hipMemcpyDeviceToDevice, stream);
  k_rmsnorm<<<M_TOK, 256, 0, stream>>>(x_cross, ca_norm_cross_scale, hcbuf);

  // ---- self attention ----
  k_rmsnorm<<<M_TOK, 256, 0, stream>>>(xbuf, sa_norm_scale, hbuf);
  k_gemm_nt<<<dim3(3 * DM / BN, M_TOK / BM), 256, 0, stream>>>(
      hbuf, sa_wqkv, bigbuf, nullptr, M_TOK, 3 * DM, DM);
  k_rope_cs<<<ropeGrid, 256, 0, stream>>>(bigbuf, 3 * DM, 0, pos, sa_scale, qbuf, 1, 1);
  k_rope_cs<<<ropeGrid, 256, 0, stream>>>(bigbuf, 3 * DM, DM, pos, sa_scale, kbuf, 1, 1);
  k_rope_cs<<<ropeGrid, 256, 0, stream>>>(bigbuf, 3 * DM, 2 * DM, nullptr, nullptr, vbuf, 0, 0);
  k_attn_tile<<<attnGrid, 256, 0, stream>>>(qbuf, kbuf, vbuf, obuf);
  k_gemm_nt<<<dim3(DM / BN, M_TOK / BM), 256, 0, stream>>>(
      obuf, sa_wout, xbuf, xbuf, M_TOK, DM, DM);

  // ---- cross attention ----
  k_rmsnorm<<<M_TOK, 256, 0, stream>>>(xbuf, ca_norm_scale, hbuf);
  k_gemm_nt<<<dim3(DM / BN, M_TOK / BM), 256, 0, stream>>>(
      hbuf, ca_wq, obuf, nullptr, M_TOK, DM, DM);
  k_gemm_nt<<<dim3(2 * DM / BN, M_TOK / BM), 256, 0, stream>>>(
      hcbuf, ca_wkv, bigbuf, nullptr, M_TOK, 2 * DM, DM);
  k_rope_cs<<<ropeGrid, 256, 0, stream>>>(obuf, DM, 0, pos, ca_scale, qbuf, 1, 1);
  k_rope_cs<<<ropeGrid, 256, 0, stream>>>(bigbuf, 2 * DM, 0, pos_cross, ca_scale, kbuf, 1, 1);
  k_rope_cs<<<ropeGrid, 256, 0, stream>>>(bigbuf, 2 * DM, DM, nullptr, nullptr, vbuf, 0, 0);
  k_attn_tile<<<attnGrid, 256, 0, stream>>>(qbuf, kbuf, vbuf, obuf);
  k_gemm_nt<<<dim3(DM / BN, M_TOK / BM), 256, 0, stream>>>(
      obuf, ca_wout, xbuf, xbuf, M_TOK, DM, DM);

  // ---- feed-forward ----
  k_rmsnorm<<<M_TOK, 256, 0, stream>>>(xbuf, ff_norm_scale, hbuf);
  k_gemm_nt<<<dim3(2 * DFF / BN, M_TOK / BM), 256, 0, stream>>>(
      hbuf, ff_wup, bigbuf, nullptr, M_TOK, 2 * DFF, DM);
  const int nFF = M_TOK * DFF;
  k_ffact<<<(nFF + 255) / 256, 256, 0, stream>>>(bigbuf, ffact);
  k_gemm_nt<<<dim3(DM / BN, M_TOK / BM), 256, 0, stream>>>(
      ffact, ff_wdown, out, xbuf, M_TOK, DM, DFF);
}

// Round 4
// 1284.859 us; speedup vs baseline: 8.7387x; 1.7161x over previous
//
#include <hip/hip_runtime.h>
#include <hip/hip_bf16.h>
#include <math.h>

typedef __hip_bfloat16 bf16;

#define B 2
#define L 2048
#define DM 768
#define NH 12
#define DH 64
#define DFF 2304
#define M_TOK (B * L) // 4096

typedef __attribute__((ext_vector_type(8))) short bfrag;
typedef __attribute__((ext_vector_type(4))) float ffrag;

__device__ __forceinline__ float waveSum(float v) {
#pragma unroll
  for (int o = 32; o > 0; o >>= 1) v += __shfl_down(v, o, 64);
  return v;
}

__device__ __forceinline__ unsigned short f2bu(float f) {
  bf16 h = __float2bfloat16(f);
  return __builtin_bit_cast(unsigned short, h);
}

__device__ __forceinline__ void gld16(void* l, const void* g) {
  __builtin_amdgcn_global_load_lds((const __attribute__((address_space(1))) unsigned*)g,
                                   (__attribute__((address_space(3))) unsigned*)l, 16, 0, 0);
}

// ---------- weight cast fp32 -> bf16 ----------
__global__ void k_castw(const float* __restrict__ in, bf16* __restrict__ out, int n) {
  int i = blockIdx.x * blockDim.x + threadIdx.x;
  if (i < n) out[i] = __float2bfloat16(in[i]);
}

// ---------- RMSNorm: one block (256 thr) per row of 768; bf16 out ----------
__global__ __launch_bounds__(256) void k_rmsnorm(const float* __restrict__ in,
                                                 const float* __restrict__ scale,
                                                 bf16* __restrict__ out) {
  int row = blockIdx.x;
  int t = threadIdx.x;
  const float* r = in + (size_t)row * DM;
  float x0 = r[t], x1 = r[t + 256], x2 = r[t + 512];
  float ss = x0 * x0 + x1 * x1 + x2 * x2;
  ss = waveSum(ss);
  __shared__ float red[4];
  int w = t >> 6, ln = t & 63;
  if (ln == 0) red[w] = ss;
  __syncthreads();
  float tot = red[0] + red[1] + red[2] + red[3];
  float g = rsqrtf(tot / (float)DM + 1e-6f);
  bf16* o = out + (size_t)row * DM;
  o[t] = __float2bfloat16(x0 * g * scale[t]);
  o[t + 256] = __float2bfloat16(x1 * g * scale[t + 256]);
  o[t + 512] = __float2bfloat16(x2 * g * scale[t + 512]);
}

// ---------- MFMA GEMM: C(MxN,f32) = A(MxK,bf16) @ W(NxK,bf16)^T (+res) ----------
// 128x128 tile, BK=32, 4 waves each computing 64x64 via 4x4 16x16x32 MFMAs.
// LDS XOR-swizzle: 16B chunk (row,kc) stored at kc^((row>>1)&3) -> 2-way reads (free).
__global__ __launch_bounds__(256) void k_gemm_mfma(const bf16* __restrict__ A,
                                                   const bf16* __restrict__ W,
                                                   float* __restrict__ C,
                                                   const float* __restrict__ res,
                                                   int M, int N, int K) {
  __shared__ __align__(16) bf16 As[128 * 32];
  __shared__ __align__(16) bf16 Bs[128 * 32];
  const int t = threadIdx.x;
  const int w = t >> 6, lane = t & 63;
  const int m0 = blockIdx.y * 128, n0 = blockIdx.x * 128;
  const int wm = w >> 1, wn = w & 1;
  const int quad = lane >> 4, l16 = lane & 15;

  ffrag acc[4][4];
#pragma unroll
  for (int i = 0; i < 4; i++)
#pragma unroll
    for (int j = 0; j < 4; j++) acc[i][j] = (ffrag){0.f, 0.f, 0.f, 0.f};

  // staging: instruction q (0..7) covers LDS bytes q*1024 + lane*16
  const int srow = (w * 2) * 16 + (lane >> 2); // row for it=0; it=1 adds 16
  for (int k0 = 0; k0 < K; k0 += 32) {
#pragma unroll
    for (int it = 0; it < 2; it++) {
      int q = w * 2 + it;
      int row = srow + it * 16;
      int kc = (lane & 3) ^ ((row >> 1) & 3);
      gld16(&As[q * 512 + lane * 8], &A[(size_t)(m0 + row) * K + k0 + kc * 8]);
      gld16(&Bs[q * 512 + lane * 8], &W[(size_t)(n0 + row) * K + k0 + kc * 8]);
    }
    __syncthreads();
    bfrag af[4], bfv[4];
#pragma unroll
    for (int i = 0; i < 4; i++) {
      int r = wm * 64 + i * 16 + l16;
      af[i] = *(const bfrag*)&As[r * 32 + (quad ^ ((r >> 1) & 3)) * 8];
    }
#pragma unroll
    for (int j = 0; j < 4; j++) {
      int r = wn * 64 + j * 16 + l16;
      bfv[j] = *(const bfrag*)&Bs[r * 32 + (quad ^ ((r >> 1) & 3)) * 8];
    }
#pragma unroll
    for (int i = 0; i < 4; i++)
#pragma unroll
      for (int j = 0; j < 4; j++)
        acc[i][j] = __builtin_amdgcn_mfma_f32_16x16x32_bf16(af[i], bfv[j], acc[i][j], 0, 0, 0);
    __syncthreads();
  }
  // epilogue: C/D layout col=lane&15, row=quad*4+reg
#pragma unroll
  for (int i = 0; i < 4; i++) {
    int mrow = m0 + wm * 64 + i * 16 + quad * 4;
#pragma unroll
    for (int j = 0; j < 4; j++) {
      int ncol = n0 + wn * 64 + j * 16 + l16;
#pragma unroll
      for (int r = 0; r < 4; r++) {
        float v = acc[i][j][r];
        size_t idx = (size_t)(mrow + r) * N + ncol;
        if (res) v += res[idx];
        C[idx] = v;
      }
    }
  }
}

// ---------- cos-scale + RoPE; one wave per (b,h,l) ----------
// transpose=1: out layout (bh, d, L)  [for Q,K feeding tiled attention]
// transpose=0: out layout (bh, L, d)  [for V]
__global__ __launch_bounds__(256) void k_rope_cs(const float* __restrict__ in, int in_stride,
                                                 int in_off, const float* __restrict__ pos,
                                                 const float* __restrict__ scale,
                                                 float* __restrict__ out, int do_rope,
                                                 int transpose) {
  int item = blockIdx.x * 4 + (threadIdx.x >> 6); // item = (b*NH + h)*L + l
  int lane = threadIdx.x & 63;
  int l = item % L;
  int bh = item / L;
  int h = bh % NH;
  int b = bh / NH;
  float x = in[(size_t)(b * L + l) * in_stride + in_off + h * DH + lane];
  float o;
  if (do_rope) {
    float ss = x * x;
#pragma unroll
    for (int m = 32; m > 0; m >>= 1) ss += __shfl_xor(ss, m, 64);
    float s = sqrtf(scale[h]);
    x *= s * rsqrtf(ss + 1e-6f);
    int j = lane < 24 ? lane : (lane < 48 ? lane - 24 : 0);
    int partner = lane < 24 ? lane + 24 : (lane < 48 ? lane - 24 : lane);
    float other = __shfl(x, partner, 64);
    if (lane < 48) {
      int c = j >> 3, f = j & 7;
      // ROPE_FREQS[h][f] = pi * 10^((f*12+h)/96)
      float fr = __expf(1.14472988584940017f +
                        (float)(f * 12 + h) * (2.30258509299404568f / 96.0f));
      float th = pos[(size_t)(b * L + l) * 3 + c] * fr;
      float st, ct;
      sincosf(th, &st, &ct);
      o = (lane < 24) ? (x * ct - other * st) : (x * ct + other * st);
    } else {
      o = x;
    }
  } else {
    o = x;
  }
  if (transpose)
    out[((size_t)bh * DH + lane) * L + l] = o;
  else
    out[(size_t)item * DH + lane] = o;
}

// ---------- tiled flash attention ----------
// Qt, Kt: (B*NH, DH, L) transposed; V: (B*NH, L, DH); O: (B, L, NH, DH) bf16
#define PADT 68
__global__ __launch_bounds__(256) void k_attn_tile(const float* __restrict__ Qt,
                                                   const float* __restrict__ Kt,
                                                   const float* __restrict__ V,
                                                   bf16* __restrict__ O) {
  __shared__ float Qs[DH][PADT];  // [d][q]
  __shared__ float KV[64][PADT];  // K phase: [d][k]; V phase: [k][d]
  __shared__ float St[64][PADT];  // [q][k]  (p-values)
  int qt = blockIdx.x & 31;       // L/64
  int bh = blockIdx.x >> 5;
  int t = threadIdx.x;
  int tx = t & 15, ty = t >> 4;   // 16x16 threads, 4x4 patches
  int r0 = t >> 4, c0 = t & 15;   // staging: row r0(+16*it), float4 col c0

  const float* qbase = Qt + ((size_t)bh * DH) * L + qt * 64;
#pragma unroll
  for (int it = 0; it < 4; it++) {
    int d = r0 + it * 16;
    *(float4*)&Qs[d][c0 * 4] = *(const float4*)&qbase[(size_t)d * L + c0 * 4];
  }

  float o[4][4] = {};
  float m_run[4], l_run[4];
#pragma unroll
  for (int i = 0; i < 4; i++) { m_run[i] = -1e30f; l_run[i] = 0.f; }

  const float* kbase = Kt + ((size_t)bh * DH) * L;
  const float* vbase = V + ((size_t)bh * L) * DH;

  for (int kt = 0; kt < 32; kt++) {
    int k0 = kt * 64;
    __syncthreads();
#pragma unroll
    for (int it = 0; it < 4; it++) {
      int d = r0 + it * 16;
      *(float4*)&KV[d][c0 * 4] = *(const float4*)&kbase[(size_t)d * L + k0 + c0 * 4];
    }
    __syncthreads();
    float s[4][4] = {};
#pragma unroll 8
    for (int d = 0; d < DH; d++) {
      float4 a = *(const float4*)&Qs[d][ty * 4];
      float4 b = *(const float4*)&KV[d][tx * 4];
      float av[4] = {a.x, a.y, a.z, a.w};
      float bv[4] = {b.x, b.y, b.z, b.w};
#pragma unroll
      for (int i = 0; i < 4; i++)
#pragma unroll
        for (int j = 0; j < 4; j++) s[i][j] += av[i] * bv[j];
    }
    __syncthreads();
#pragma unroll
    for (int it = 0; it < 4; it++) {
      int k = r0 + it * 16;
      *(float4*)&KV[k][c0 * 4] = *(const float4*)&vbase[(size_t)(k0 + k) * DH + c0 * 4];
    }
#pragma unroll
    for (int i = 0; i < 4; i++) {
      float rm = fmaxf(fmaxf(s[i][0], s[i][1]), fmaxf(s[i][2], s[i][3]));
#pragma unroll
      for (int msk = 1; msk < 16; msk <<= 1) rm = fmaxf(rm, __shfl_xor(rm, msk, 64));
      float mn = fmaxf(m_run[i], rm);
      float alpha = __expf(m_run[i] - mn);
      float p0 = __expf(s[i][0] - mn), p1 = __expf(s[i][1] - mn);
      float p2 = __expf(s[i][2] - mn), p3 = __expf(s[i][3] - mn);
      float rs = p0 + p1 + p2 + p3;
#pragma unroll
      for (int msk = 1; msk < 16; msk <<= 1) rs += __shfl_xor(rs, msk, 64);
      l_run[i] = l_run[i] * alpha + rs;
      m_run[i] = mn;
#pragma unroll
      for (int j = 0; j < 4; j++) o[i][j] *= alpha;
      float4 pv = {p0, p1, p2, p3};
      *(float4*)&St[ty * 4 + i][tx * 4] = pv;
    }
    __syncthreads();
#pragma unroll 4
    for (int kk = 0; kk < 64; kk += 4) {
      float4 a0 = *(const float4*)&St[ty * 4 + 0][kk];
      float4 a1 = *(const float4*)&St[ty * 4 + 1][kk];
      float4 a2 = *(const float4*)&St[ty * 4 + 2][kk];
      float4 a3 = *(const float4*)&St[ty * 4 + 3][kk];
      float4 b0 = *(const float4*)&KV[kk + 0][tx * 4];
      float4 b1 = *(const float4*)&KV[kk + 1][tx * 4];
      float4 b2 = *(const float4*)&KV[kk + 2][tx * 4];
      float4 b3 = *(const float4*)&KV[kk + 3][tx * 4];
      float am[4][4] = {{a0.x, a0.y, a0.z, a0.w}, {a1.x, a1.y, a1.z, a1.w},
                        {a2.x, a2.y, a2.z, a2.w}, {a3.x, a3.y, a3.z, a3.w}};
      float bm[4][4] = {{b0.x, b0.y, b0.z, b0.w}, {b1.x, b1.y, b1.z, b1.w},
                        {b2.x, b2.y, b2.z, b2.w}, {b3.x, b3.y, b3.z, b3.w}};
#pragma unroll
      for (int c = 0; c < 4; c++)
#pragma unroll
        for (int i = 0; i < 4; i++)
#pragma unroll
          for (int j = 0; j < 4; j++) o[i][j] += am[i][c] * bm[c][j];
    }
  }
  int b = bh / NH, h = bh % NH;
#pragma unroll
  for (int i = 0; i < 4; i++) {
    float inv = 1.f / l_run[i];
    int l = qt * 64 + ty * 4 + i;
    ushort4 pk = {f2bu(o[i][0] * inv), f2bu(o[i][1] * inv),
                  f2bu(o[i][2] * inv), f2bu(o[i][3] * inv)};
    *(ushort4*)&O[(((size_t)b * L + l) * NH + h) * DH + tx * 4] = pk;
  }
}

// ---------- SwiGLU: out[m,j] = a * silu(g), bf16 out ----------
__global__ void k_ffact(const float* __restrict__ U, bf16* __restrict__ Out) {
  int idx = blockIdx.x * blockDim.x + threadIdx.x;
  int total = M_TOK * DFF;
  if (idx >= total) return;
  int mrow = idx / DFF, jj = idx % DFF;
  float a = U[(size_t)mrow * (2 * DFF) + jj];
  float g = U[(size_t)mrow * (2 * DFF) + DFF + jj];
  Out[idx] = __float2bfloat16(a * g / (1.f + __expf(-g)));
}

extern "C" void kernel_launch(void* const* d_in, const int* in_sizes, int n_in,
                              void* d_out, int out_size, void* d_ws, size_t ws_size,
                              hipStream_t stream) {
  const float* x = (const float*)d_in[0];
  const float* pos = (const float*)d_in[1];
  const float* x_cross = (const float*)d_in[2];
  const float* pos_cross = (const float*)d_in[3];
  const float* sa_norm_scale = (const float*)d_in[4];
  const float* sa_wqkv = (const float*)d_in[5];
  const float* sa_scale = (const float*)d_in[6];
  const float* sa_wout = (const float*)d_in[7];
  const float* ca_norm_scale = (const float*)d_in[8];
  const float* ca_norm_cross_scale = (const float*)d_in[9];
  const float* ca_wq = (const float*)d_in[10];
  const float* ca_wkv = (const float*)d_in[11];
  const float* ca_scale = (const float*)d_in[12];
  const float* ca_wout = (const float*)d_in[13];
  const float* ff_norm_scale = (const float*)d_in[14];
  const float* ff_wup = (const float*)d_in[15];
  const float* ff_wdown = (const float*)d_in[16];
  float* out = (float*)d_out;

  float* ws = (float*)d_ws;
  const size_t S = (size_t)M_TOK * DM; // 3,145,728
  float* xbuf = ws;             // S : running residual (f32)
  float* qbuf = ws + S;         // (BH, DH, L)
  float* kbuf = ws + 2 * S;     // (BH, DH, L)
  float* vbuf = ws + 3 * S;     // (BH, L, DH)  / ca_wq temp
  float* bigbuf = ws + 4 * S;   // 6S: qkv / kv / ff-up
  bf16* hcb = (bf16*)(ws + 9 * S);      // cross-norm bf16 (tail of bigbuf, dead by FF)
  bf16* hb = (bf16*)(ws + 10 * S);      // S bf16
  bf16* obb = hb + S;                   // S bf16: attn out
  bf16* wqkvb = obb + S;
  bf16* woutb = wqkvb + (size_t)3 * DM * DM;
  bf16* wqb = woutb + (size_t)DM * DM;
  bf16* wkvb = wqb + (size_t)DM * DM;
  bf16* wout2b = wkvb + (size_t)2 * DM * DM;
  bf16* wupb = wout2b + (size_t)DM * DM;
  bf16* wdownb = wupb + (size_t)2 * DFF * DM;
  bf16* ffb = (bf16*)(ws + S);          // aliases qbuf/kbuf in FF phase (3S bf16)

  const int ropeGrid = B * NH * L / 4;
  const int attnGrid = B * NH * (L / 64); // 768

#define CAST(src, dst, n) k_castw<<<((n) + 255) / 256, 256, 0, stream>>>(src, dst, n)
  CAST(sa_wqkv, wqkvb, 3 * DM * DM);
  CAST(sa_wout, woutb, DM * DM);
  CAST(ca_wq, wqb, DM * DM);
  CAST(ca_wkv, wkvb, 2 * DM * DM);
  CAST(ca_wout, wout2b, DM * DM);
  CAST(ff_wup, wupb, 2 * DFF * DM);
  CAST(ff_wdown, wdownb, DM * DFF);
#undef CAST

  // ---- prologue: residual init + cross norm ----
  hipMemcpyAsync(xbuf, x, S * sizeof(float), hipMemcpyDeviceToDevice, stream);
  k_rmsnorm<<<M_TOK, 256, 0, stream>>>(x_cross, ca_norm_cross_scale, hcb);

  // ---- self attention ----
  k_rmsnorm<<<M_TOK, 256, 0, stream>>>(xbuf, sa_norm_scale, hb);
  k_gemm_mfma<<<dim3(3 * DM / 128, M_TOK / 128), 256, 0, stream>>>(
      hb, wqkvb, bigbuf, nullptr, M_TOK, 3 * DM, DM);
  k_rope_cs<<<ropeGrid, 256, 0, stream>>>(bigbuf, 3 * DM, 0, pos, sa_scale, qbuf, 1, 1);
  k_rope_cs<<<ropeGrid, 256, 0, stream>>>(bigbuf, 3 * DM, DM, pos, sa_scale, kbuf, 1, 1);
  k_rope_cs<<<ropeGrid, 256, 0, stream>>>(bigbuf, 3 * DM, 2 * DM, nullptr, nullptr, vbuf, 0, 0);
  k_attn_tile<<<attnGrid, 256, 0, stream>>>(qbuf, kbuf, vbuf, obb);
  k_gemm_mfma<<<dim3(DM / 128, M_TOK / 128), 256, 0, stream>>>(
      obb, woutb, xbuf, xbuf, M_TOK, DM, DM);

  // ---- cross attention ----
  k_rmsnorm<<<M_TOK, 256, 0, stream>>>(xbuf, ca_norm_scale, hb);
  k_gemm_mfma<<<dim3(DM / 128, M_TOK / 128), 256, 0, stream>>>(
      hb, wqb, vbuf, nullptr, M_TOK, DM, DM);
  k_gemm_mfma<<<dim3(2 * DM / 128, M_TOK / 128), 256, 0, stream>>>(
      hcb, wkvb, bigbuf, nullptr, M_TOK, 2 * DM, DM);
  k_rope_cs<<<ropeGrid, 256, 0, stream>>>(vbuf, DM, 0, pos, ca_scale, qbuf, 1, 1);
  k_rope_cs<<<ropeGrid, 256, 0, stream>>>(bigbuf, 2 * DM, 0, pos_cross, ca_scale, kbuf, 1, 1);
  k_rope_cs<<<ropeGrid, 256, 0, stream>>>(bigbuf, 2 * DM, DM, nullptr, nullptr, vbuf, 0, 0);
  k_attn_tile<<<attnGrid, 256, 0, stream>>>(qbuf, kbuf, vbuf, obb);
  k_gemm_mfma<<<dim3(DM / 128, M_TOK / 128), 256, 0, stream>>>(
      obb, wout2b, xbuf, xbuf, M_TOK, DM, DM);

  // ---- feed-forward ----
  k_rmsnorm<<<M_TOK, 256, 0, stream>>>(xbuf, ff_norm_scale, hb);
  k_gemm_mfma<<<dim3(2 * DFF / 128, M_TOK / 128), 256, 0, stream>>>(
      hb, wupb, bigbuf, nullptr, M_TOK, 2 * DFF, DM);
  const int nFF = M_TOK * DFF;
  k_ffact<<<(nFF + 255) / 256, 256, 0, stream>>>(bigbuf, ffb);
  k_gemm_mfma<<<dim3(DM / 128, M_TOK / 128), 256, 0, stream>>>(
      ffb, wdownb, out, xbuf, M_TOK, DM, DFF);
}

// Round 5
// 780.684 us; speedup vs baseline: 14.3822x; 1.6458x over previous
//
#include <hip/hip_runtime.h>
#include <hip/hip_bf16.h>
#include <math.h>

typedef __hip_bfloat16 bf16;

#define B 2
#define L 2048
#define DM 768
#define NH 12
#define DH 64
#define DFF 2304
#define M_TOK (B * L) // 4096

typedef __attribute__((ext_vector_type(8))) short bfrag;
typedef __attribute__((ext_vector_type(4))) float ffrag;

__device__ __forceinline__ float waveSum(float v) {
#pragma unroll
  for (int o = 32; o > 0; o >>= 1) v += __shfl_down(v, o, 64);
  return v;
}

__device__ __forceinline__ unsigned short f2bu(float f) {
  bf16 h = __float2bfloat16(f);
  return __builtin_bit_cast(unsigned short, h);
}

__device__ __forceinline__ void gld16(void* l, const void* g) {
  __builtin_amdgcn_global_load_lds((const __attribute__((address_space(1))) unsigned*)g,
                                   (__attribute__((address_space(3))) unsigned*)l, 16, 0, 0);
}

// ---------- weight cast fp32 -> bf16 ----------
__global__ void k_castw(const float* __restrict__ in, bf16* __restrict__ out, int n) {
  int i = blockIdx.x * blockDim.x + threadIdx.x;
  if (i < n) out[i] = __float2bfloat16(in[i]);
}

// ---------- RMSNorm: one block (256 thr) per row of 768; bf16 out ----------
__global__ __launch_bounds__(256) void k_rmsnorm(const float* __restrict__ in,
                                                 const float* __restrict__ scale,
                                                 bf16* __restrict__ out) {
  int row = blockIdx.x;
  int t = threadIdx.x;
  const float* r = in + (size_t)row * DM;
  float x0 = r[t], x1 = r[t + 256], x2 = r[t + 512];
  float ss = x0 * x0 + x1 * x1 + x2 * x2;
  ss = waveSum(ss);
  __shared__ float red[4];
  int w = t >> 6, ln = t & 63;
  if (ln == 0) red[w] = ss;
  __syncthreads();
  float tot = red[0] + red[1] + red[2] + red[3];
  float g = rsqrtf(tot / (float)DM + 1e-6f);
  bf16* o = out + (size_t)row * DM;
  o[t] = __float2bfloat16(x0 * g * scale[t]);
  o[t + 256] = __float2bfloat16(x1 * g * scale[t + 256]);
  o[t + 512] = __float2bfloat16(x2 * g * scale[t + 512]);
}

// ---------- MFMA GEMM: C(MxN,f32) = A(MxK,bf16) @ W(NxK,bf16)^T (+res) ----------
__global__ __launch_bounds__(256) void k_gemm_mfma(const bf16* __restrict__ A,
                                                   const bf16* __restrict__ W,
                                                   float* __restrict__ C,
                                                   const float* __restrict__ res,
                                                   int M, int N, int K) {
  __shared__ __align__(16) bf16 As[128 * 32];
  __shared__ __align__(16) bf16 Bs[128 * 32];
  const int t = threadIdx.x;
  const int w = t >> 6, lane = t & 63;
  const int m0 = blockIdx.y * 128, n0 = blockIdx.x * 128;
  const int wm = w >> 1, wn = w & 1;
  const int quad = lane >> 4, l16 = lane & 15;

  ffrag acc[4][4];
#pragma unroll
  for (int i = 0; i < 4; i++)
#pragma unroll
    for (int j = 0; j < 4; j++) acc[i][j] = (ffrag){0.f, 0.f, 0.f, 0.f};

  const int srow = (w * 2) * 16 + (lane >> 2);
  for (int k0 = 0; k0 < K; k0 += 32) {
#pragma unroll
    for (int it = 0; it < 2; it++) {
      int q = w * 2 + it;
      int row = srow + it * 16;
      int kc = (lane & 3) ^ ((row >> 1) & 3);
      gld16(&As[q * 512 + lane * 8], &A[(size_t)(m0 + row) * K + k0 + kc * 8]);
      gld16(&Bs[q * 512 + lane * 8], &W[(size_t)(n0 + row) * K + k0 + kc * 8]);
    }
    __syncthreads();
    bfrag af[4], bfv[4];
#pragma unroll
    for (int i = 0; i < 4; i++) {
      int r = wm * 64 + i * 16 + l16;
      af[i] = *(const bfrag*)&As[r * 32 + (quad ^ ((r >> 1) & 3)) * 8];
    }
#pragma unroll
    for (int j = 0; j < 4; j++) {
      int r = wn * 64 + j * 16 + l16;
      bfv[j] = *(const bfrag*)&Bs[r * 32 + (quad ^ ((r >> 1) & 3)) * 8];
    }
#pragma unroll
    for (int i = 0; i < 4; i++)
#pragma unroll
      for (int j = 0; j < 4; j++)
        acc[i][j] = __builtin_amdgcn_mfma_f32_16x16x32_bf16(af[i], bfv[j], acc[i][j], 0, 0, 0);
    __syncthreads();
  }
#pragma unroll
  for (int i = 0; i < 4; i++) {
    int mrow = m0 + wm * 64 + i * 16 + quad * 4;
#pragma unroll
    for (int j = 0; j < 4; j++) {
      int ncol = n0 + wn * 64 + j * 16 + l16;
#pragma unroll
      for (int r = 0; r < 4; r++) {
        float v = acc[i][j][r];
        size_t idx = (size_t)(mrow + r) * N + ncol;
        if (res) v += res[idx];
        C[idx] = v;
      }
    }
  }
}

// ---------- cos-scale + RoPE; one wave per (b,h,l); bf16 out ----------
// transpose=0: out (bh, L, DH)  [Q, K]
// transpose=1: out (bh, DH, L)  [V for PV B-operand]
__global__ __launch_bounds__(256) void k_rope_cs(const float* __restrict__ in, int in_stride,
                                                 int in_off, const float* __restrict__ pos,
                                                 const float* __restrict__ scale,
                                                 bf16* __restrict__ out, int do_rope,
                                                 int transpose) {
  int item = blockIdx.x * 4 + (threadIdx.x >> 6); // item = (b*NH + h)*L + l
  int lane = threadIdx.x & 63;
  int l = item % L;
  int bh = item / L;
  int h = bh % NH;
  int b = bh / NH;
  float x = in[(size_t)(b * L + l) * in_stride + in_off + h * DH + lane];
  float o;
  if (do_rope) {
    float ss = x * x;
#pragma unroll
    for (int m = 32; m > 0; m >>= 1) ss += __shfl_xor(ss, m, 64);
    float s = sqrtf(scale[h]);
    x *= s * rsqrtf(ss + 1e-6f);
    int j = lane < 24 ? lane : (lane < 48 ? lane - 24 : 0);
    int partner = lane < 24 ? lane + 24 : (lane < 48 ? lane - 24 : lane);
    float other = __shfl(x, partner, 64);
    if (lane < 48) {
      int c = j >> 3, f = j & 7;
      // ROPE_FREQS[h][f] = pi * 10^((f*12+h)/96)
      float fr = __expf(1.14472988584940017f +
                        (float)(f * 12 + h) * (2.30258509299404568f / 96.0f));
      float th = pos[(size_t)(b * L + l) * 3 + c] * fr;
      float st, ct;
      sincosf(th, &st, &ct);
      o = (lane < 24) ? (x * ct - other * st) : (x * ct + other * st);
    } else {
      o = x;
    }
  } else {
    o = x;
  }
  if (transpose)
    out[((size_t)bh * DH + lane) * L + l] = __float2bfloat16(o);
  else
    out[(size_t)item * DH + lane] = __float2bfloat16(o);
}

// ---------- MFMA flash attention ----------
// Q,K: (BH, L, DH) bf16; Vt: (BH, DH, L) bf16; O: (B, L, NH, DH) bf16
// block = 4 waves = 64 queries; wave w owns queries w*16..w*16+15.
#define LKP 72  // padded LDS row: 72 bf16 = 144 B (16B-aligned, bank-uniform)
__global__ __launch_bounds__(256) void k_attn_mfma(const bf16* __restrict__ Q,
                                                   const bf16* __restrict__ K,
                                                   const bf16* __restrict__ Vt,
                                                   bf16* __restrict__ O) {
  __shared__ __align__(16) bf16 Ks[64 * LKP];
  __shared__ __align__(16) bf16 Vs[64 * LKP];
  __shared__ __align__(16) bf16 Ps[64 * LKP];
  int qt = blockIdx.x & 31, bh = blockIdx.x >> 5;
  int t = threadIdx.x, w = t >> 6, lane = t & 63;
  int quad = lane >> 4, l16 = lane & 15;

  // Q A-fragments, held in registers for the whole kernel
  const bf16* qrow = Q + ((size_t)(bh * L) + qt * 64 + w * 16 + l16) * DH;
  bfrag qf0 = *(const bfrag*)&qrow[quad * 8];
  bfrag qf1 = *(const bfrag*)&qrow[32 + quad * 8];

  ffrag o_acc[4];
#pragma unroll
  for (int j = 0; j < 4; j++) o_acc[j] = (ffrag){0.f, 0.f, 0.f, 0.f};
  float m_run[4], l_run[4];
#pragma unroll
  for (int i = 0; i < 4; i++) { m_run[i] = -1e30f; l_run[i] = 0.f; }

  const bf16* kbase = K + (size_t)(bh * L) * DH;
  const bf16* vbase = Vt + (size_t)bh * DH * L;

  for (int kt = 0; kt < 32; kt++) {
    int k0 = kt * 64;
    __syncthreads();  // prev iter PV reads of Ps/Vs + S reads of Ks done
    // ---- stage K [key][d] and V [d][key] (2 chunks each per thread) ----
#pragma unroll
    for (int half = 0; half < 2; half++) {
      int cid = t + half * 256;
      int r = cid >> 3, c = cid & 7;
      *(float4*)&Ks[r * LKP + c * 8] = *(const float4*)&kbase[(size_t)(k0 + r) * DH + c * 8];
      *(float4*)&Vs[r * LKP + c * 8] = *(const float4*)&vbase[(size_t)r * L + k0 + c * 8];
    }
    __syncthreads();
    // ---- S = Q K^T : 4 key sub-tiles ----
    ffrag s_acc[4];
#pragma unroll
    for (int j = 0; j < 4; j++) {
      bfrag kf0 = *(const bfrag*)&Ks[(j * 16 + l16) * LKP + quad * 8];
      bfrag kf1 = *(const bfrag*)&Ks[(j * 16 + l16) * LKP + 32 + quad * 8];
      ffrag z = (ffrag){0.f, 0.f, 0.f, 0.f};
      z = __builtin_amdgcn_mfma_f32_16x16x32_bf16(qf0, kf0, z, 0, 0, 0);
      z = __builtin_amdgcn_mfma_f32_16x16x32_bf16(qf1, kf1, z, 0, 0, 0);
      s_acc[j] = z;
    }
    // ---- online softmax (rows q = quad*4+reg, stats replicated over l16) ----
    float alpha[4];
#pragma unroll
    for (int reg = 0; reg < 4; reg++) {
      float rm = fmaxf(fmaxf(s_acc[0][reg], s_acc[1][reg]),
                       fmaxf(s_acc[2][reg], s_acc[3][reg]));
#pragma unroll
      for (int msk = 1; msk < 16; msk <<= 1) rm = fmaxf(rm, __shfl_xor(rm, msk, 64));
      float mn = fmaxf(m_run[reg], rm);
      alpha[reg] = __expf(m_run[reg] - mn);
      m_run[reg] = mn;
      float rs = 0.f;
#pragma unroll
      for (int j = 0; j < 4; j++) {
        float p = __expf(s_acc[j][reg] - mn);
        s_acc[j][reg] = p;
        rs += p;
      }
#pragma unroll
      for (int msk = 1; msk < 16; msk <<= 1) rs += __shfl_xor(rs, msk, 64);
      l_run[reg] = l_run[reg] * alpha[reg] + rs;
    }
#pragma unroll
    for (int jd = 0; jd < 4; jd++)
#pragma unroll
      for (int reg = 0; reg < 4; reg++) o_acc[jd][reg] *= alpha[reg];
    // ---- write P to LDS (bf16, paired into 32-bit words via neighbor shfl) ----
#pragma unroll
    for (int j = 0; j < 4; j++) {
#pragma unroll
      for (int reg = 0; reg < 4; reg++) {
        unsigned short myp = f2bu(s_acc[j][reg]);
        unsigned short op = (unsigned short)__shfl_xor((int)myp, 1, 64);
        unsigned int word = (l16 & 1) ? ((unsigned)op | ((unsigned)myp << 16))
                                      : ((unsigned)myp | ((unsigned)op << 16));
        if ((l16 & 1) == (reg >> 1)) {
          int qr = w * 16 + quad * 4 + reg;
          int key = j * 16 + (l16 & ~1);
          *(unsigned*)&Ps[qr * LKP + key] = word;
        }
      }
    }
    __syncthreads();  // Ps visible
    // ---- O += P V ----
    bfrag pf0 = *(const bfrag*)&Ps[(w * 16 + l16) * LKP + quad * 8];
    bfrag pf1 = *(const bfrag*)&Ps[(w * 16 + l16) * LKP + 32 + quad * 8];
#pragma unroll
    for (int jd = 0; jd < 4; jd++) {
      bfrag vf0 = *(const bfrag*)&Vs[(jd * 16 + l16) * LKP + quad * 8];
      bfrag vf1 = *(const bfrag*)&Vs[(jd * 16 + l16) * LKP + 32 + quad * 8];
      o_acc[jd] = __builtin_amdgcn_mfma_f32_16x16x32_bf16(pf0, vf0, o_acc[jd], 0, 0, 0);
      o_acc[jd] = __builtin_amdgcn_mfma_f32_16x16x32_bf16(pf1, vf1, o_acc[jd], 0, 0, 0);
    }
  }
  // ---- epilogue: normalize + store (B,L,NH,DH) bf16 ----
  int b = bh / NH, h = bh % NH;
#pragma unroll
  for (int reg = 0; reg < 4; reg++) {
    float inv = 1.f / l_run[reg];
    int l = qt * 64 + w * 16 + quad * 4 + reg;
#pragma unroll
    for (int jd = 0; jd < 4; jd++) {
      int d = jd * 16 + l16;
      O[(((size_t)b * L + l) * NH + h) * DH + d] = __float2bfloat16(o_acc[jd][reg] * inv);
    }
  }
}

// ---------- SwiGLU: out[m,j] = a * silu(g), bf16 out ----------
__global__ void k_ffact(const float* __restrict__ U, bf16* __restrict__ Out) {
  int idx = blockIdx.x * blockDim.x + threadIdx.x;
  int total = M_TOK * DFF;
  if (idx >= total) return;
  int mrow = idx / DFF, jj = idx % DFF;
  float a = U[(size_t)mrow * (2 * DFF) + jj];
  float g = U[(size_t)mrow * (2 * DFF) + DFF + jj];
  Out[idx] = __float2bfloat16(a * g / (1.f + __expf(-g)));
}

extern "C" void kernel_launch(void* const* d_in, const int* in_sizes, int n_in,
                              void* d_out, int out_size, void* d_ws, size_t ws_size,
                              hipStream_t stream) {
  const float* x = (const float*)d_in[0];
  const float* pos = (const float*)d_in[1];
  const float* x_cross = (const float*)d_in[2];
  const float* pos_cross = (const float*)d_in[3];
  const float* sa_norm_scale = (const float*)d_in[4];
  const float* sa_wqkv = (const float*)d_in[5];
  const float* sa_scale = (const float*)d_in[6];
  const float* sa_wout = (const float*)d_in[7];
  const float* ca_norm_scale = (const float*)d_in[8];
  const float* ca_norm_cross_scale = (const float*)d_in[9];
  const float* ca_wq = (const float*)d_in[10];
  const float* ca_wkv = (const float*)d_in[11];
  const float* ca_scale = (const float*)d_in[12];
  const float* ca_wout = (const float*)d_in[13];
  const float* ff_norm_scale = (const float*)d_in[14];
  const float* ff_wup = (const float*)d_in[15];
  const float* ff_wdown = (const float*)d_in[16];
  float* out = (float*)d_out;

  float* ws = (float*)d_ws;
  const size_t S = (size_t)M_TOK * DM; // 3,145,728
  float* xbuf = ws;             // S : running residual (f32)
  float* bigbuf = ws + S;       // 6S f32: qkv / kv+caq / ff-up
  float* caq = bigbuf + 2 * S;  // ca q-proj out (f32, S) while kv in bigbuf[0,2S)
  bf16* b16 = (bf16*)(ws + 7 * S);
  bf16* qb = b16;               // (BH, L, DH)
  bf16* kb = b16 + S;           // (BH, L, DH)
  bf16* vtb = b16 + 2 * S;      // (BH, DH, L)
  bf16* hb = b16 + 3 * S;
  bf16* hcb = b16 + 4 * S;
  bf16* obb = b16 + 5 * S;      // attn out (B,L,NH,DH)
  bf16* wqkvb = b16 + 6 * S;
  bf16* woutb = wqkvb + (size_t)3 * DM * DM;
  bf16* wqb = woutb + (size_t)DM * DM;
  bf16* wkvb = wqb + (size_t)DM * DM;
  bf16* wout2b = wkvb + (size_t)2 * DM * DM;
  bf16* wupb = wout2b + (size_t)DM * DM;
  bf16* wdownb = wupb + (size_t)2 * DFF * DM;
  bf16* ffb = b16;              // aliases qb/kb/vtb (dead in FF phase), 3S bf16

  const int ropeGrid = B * NH * L / 4;
  const int attnGrid = B * NH * (L / 64); // 768

#define CAST(src, dst, n) k_castw<<<((n) + 255) / 256, 256, 0, stream>>>(src, dst, n)
  CAST(sa_wqkv, wqkvb, 3 * DM * DM);
  CAST(sa_wout, woutb, DM * DM);
  CAST(ca_wq, wqb, DM * DM);
  CAST(ca_wkv, wkvb, 2 * DM * DM);
  CAST(ca_wout, wout2b, DM * DM);
  CAST(ff_wup, wupb, 2 * DFF * DM);
  CAST(ff_wdown, wdownb, DM * DFF);
#undef CAST

  // ---- prologue: residual init + cross norm ----
  hipMemcpyAsync(xbuf, x, S * sizeof(float), hipMemcpyDeviceToDevice, stream);
  k_rmsnorm<<<M_TOK, 256, 0, stream>>>(x_cross, ca_norm_cross_scale, hcb);

  // ---- self attention ----
  k_rmsnorm<<<M_TOK, 256, 0, stream>>>(xbuf, sa_norm_scale, hb);
  k_gemm_mfma<<<dim3(3 * DM / 128, M_TOK / 128), 256, 0, stream>>>(
      hb, wqkvb, bigbuf, nullptr, M_TOK, 3 * DM, DM);
  k_rope_cs<<<ropeGrid, 256, 0, stream>>>(bigbuf, 3 * DM, 0, pos, sa_scale, qb, 1, 0);
  k_rope_cs<<<ropeGrid, 256, 0, stream>>>(bigbuf, 3 * DM, DM, pos, sa_scale, kb, 1, 0);
  k_rope_cs<<<ropeGrid, 256, 0, stream>>>(bigbuf, 3 * DM, 2 * DM, nullptr, nullptr, vtb, 0, 1);
  k_attn_mfma<<<attnGrid, 256, 0, stream>>>(qb, kb, vtb, obb);
  k_gemm_mfma<<<dim3(DM / 128, M_TOK / 128), 256, 0, stream>>>(
      obb, woutb, xbuf, xbuf, M_TOK, DM, DM);

  // ---- cross attention ----
  k_rmsnorm<<<M_TOK, 256, 0, stream>>>(xbuf, ca_norm_scale, hb);
  k_gemm_mfma<<<dim3(DM / 128, M_TOK / 128), 256, 0, stream>>>(
      hb, wqb, caq, nullptr, M_TOK, DM, DM);
  k_gemm_mfma<<<dim3(2 * DM / 128, M_TOK / 128), 256, 0, stream>>>(
      hcb, wkvb, bigbuf, nullptr, M_TOK, 2 * DM, DM);
  k_rope_cs<<<ropeGrid, 256, 0, stream>>>(caq, DM, 0, pos, ca_scale, qb, 1, 0);
  k_rope_cs<<<ropeGrid, 256, 0, stream>>>(bigbuf, 2 * DM, 0, pos_cross, ca_scale, kb, 1, 0);
  k_rope_cs<<<ropeGrid, 256, 0, stream>>>(bigbuf, 2 * DM, DM, nullptr, nullptr, vtb, 0, 1);
  k_attn_mfma<<<attnGrid, 256, 0, stream>>>(qb, kb, vtb, obb);
  k_gemm_mfma<<<dim3(DM / 128, M_TOK / 128), 256, 0, stream>>>(
      obb, wout2b, xbuf, xbuf, M_TOK, DM, DM);

  // ---- feed-forward ----
  k_rmsnorm<<<M_TOK, 256, 0, stream>>>(xbuf, ff_norm_scale, hb);
  k_gemm_mfma<<<dim3(2 * DFF / 128, M_TOK / 128), 256, 0, stream>>>(
      hb, wupb, bigbuf, nullptr, M_TOK, 2 * DFF, DM);
  const int nFF = M_TOK * DFF;
  k_ffact<<<(nFF + 255) / 256, 256, 0, stream>>>(bigbuf, ffb);
  k_gemm_mfma<<<dim3(DM / 128, M_TOK / 128), 256, 0, stream>>>(
      ffb, wdownb, out, xbuf, M_TOK, DM, DFF);
}

// Round 6
// 648.951 us; speedup vs baseline: 17.3017x; 1.2030x over previous
//
#include <hip/hip_runtime.h>
#include <hip/hip_bf16.h>
#include <math.h>

typedef __hip_bfloat16 bf16;

#define B 2
#define L 2048
#define DM 768
#define NH 12
#define DH 64
#define DFF 2304
#define M_TOK (B * L) // 4096

typedef __attribute__((ext_vector_type(8))) short bfrag;
typedef __attribute__((ext_vector_type(4))) float ffrag;

__device__ __forceinline__ float waveSum(float v) {
#pragma unroll
  for (int o = 32; o > 0; o >>= 1) v += __shfl_down(v, o, 64);
  return v;
}

__device__ __forceinline__ void gld16(void* l, const void* g) {
  __builtin_amdgcn_global_load_lds((const __attribute__((address_space(1))) unsigned*)g,
                                   (__attribute__((address_space(3))) unsigned*)l, 16, 0, 0);
}

// ---------- weight cast fp32 -> bf16 ----------
__global__ void k_castw(const float* __restrict__ in, bf16* __restrict__ out, int n) {
  int i = blockIdx.x * blockDim.x + threadIdx.x;
  if (i < n) out[i] = __float2bfloat16(in[i]);
}

// ---------- RMSNorm: one block (256 thr) per row of 768; bf16 out ----------
__global__ __launch_bounds__(256) void k_rmsnorm(const float* __restrict__ in,
                                                 const float* __restrict__ scale,
                                                 bf16* __restrict__ out) {
  int row = blockIdx.x;
  int t = threadIdx.x;
  const float* r = in + (size_t)row * DM;
  float x0 = r[t], x1 = r[t + 256], x2 = r[t + 512];
  float ss = x0 * x0 + x1 * x1 + x2 * x2;
  ss = waveSum(ss);
  __shared__ float red[4];
  int w = t >> 6, ln = t & 63;
  if (ln == 0) red[w] = ss;
  __syncthreads();
  float tot = red[0] + red[1] + red[2] + red[3];
  float g = rsqrtf(tot / (float)DM + 1e-6f);
  bf16* o = out + (size_t)row * DM;
  o[t] = __float2bfloat16(x0 * g * scale[t]);
  o[t + 256] = __float2bfloat16(x1 * g * scale[t + 256]);
  o[t + 512] = __float2bfloat16(x2 * g * scale[t + 512]);
}

// ---------- MFMA GEMM: C(MxN,f32) = A(MxK,bf16) @ W(NxK,bf16)^T (+res) ----------
__global__ __launch_bounds__(256) void k_gemm_mfma(const bf16* __restrict__ A,
                                                   const bf16* __restrict__ W,
                                                   float* __restrict__ C,
                                                   const float* __restrict__ res,
                                                   int M, int N, int K) {
  __shared__ __align__(16) bf16 As[128 * 32];
  __shared__ __align__(16) bf16 Bs[128 * 32];
  const int t = threadIdx.x;
  const int w = t >> 6, lane = t & 63;
  const int m0 = blockIdx.y * 128, n0 = blockIdx.x * 128;
  const int wm = w >> 1, wn = w & 1;
  const int quad = lane >> 4, l16 = lane & 15;

  ffrag acc[4][4];
#pragma unroll
  for (int i = 0; i < 4; i++)
#pragma unroll
    for (int j = 0; j < 4; j++) acc[i][j] = (ffrag){0.f, 0.f, 0.f, 0.f};

  const int srow = (w * 2) * 16 + (lane >> 2);
  for (int k0 = 0; k0 < K; k0 += 32) {
#pragma unroll
    for (int it = 0; it < 2; it++) {
      int q = w * 2 + it;
      int row = srow + it * 16;
      int kc = (lane & 3) ^ ((row >> 1) & 3);
      gld16(&As[q * 512 + lane * 8], &A[(size_t)(m0 + row) * K + k0 + kc * 8]);
      gld16(&Bs[q * 512 + lane * 8], &W[(size_t)(n0 + row) * K + k0 + kc * 8]);
    }
    __syncthreads();
    bfrag af[4], bfv[4];
#pragma unroll
    for (int i = 0; i < 4; i++) {
      int r = wm * 64 + i * 16 + l16;
      af[i] = *(const bfrag*)&As[r * 32 + (quad ^ ((r >> 1) & 3)) * 8];
    }
#pragma unroll
    for (int j = 0; j < 4; j++) {
      int r = wn * 64 + j * 16 + l16;
      bfv[j] = *(const bfrag*)&Bs[r * 32 + (quad ^ ((r >> 1) & 3)) * 8];
    }
#pragma unroll
    for (int i = 0; i < 4; i++)
#pragma unroll
      for (int j = 0; j < 4; j++)
        acc[i][j] = __builtin_amdgcn_mfma_f32_16x16x32_bf16(af[i], bfv[j], acc[i][j], 0, 0, 0);
    __syncthreads();
  }
#pragma unroll
  for (int i = 0; i < 4; i++) {
    int mrow = m0 + wm * 64 + i * 16 + quad * 4;
#pragma unroll
    for (int j = 0; j < 4; j++) {
      int ncol = n0 + wn * 64 + j * 16 + l16;
#pragma unroll
      for (int r = 0; r < 4; r++) {
        float v = acc[i][j][r];
        size_t idx = (size_t)(mrow + r) * N + ncol;
        if (res) v += res[idx];
        C[idx] = v;
      }
    }
  }
}

// ---------- cos-scale + RoPE; one wave per (b,h,l); bf16 out ----------
// transpose=0: out (bh, L, DH)  [Q, K]
// transpose=1: out (bh, DH, L)  [V for PV B-operand]
__global__ __launch_bounds__(256) void k_rope_cs(const float* __restrict__ in, int in_stride,
                                                 int in_off, const float* __restrict__ pos,
                                                 const float* __restrict__ scale,
                                                 bf16* __restrict__ out, int do_rope,
                                                 int transpose) {
  int item = blockIdx.x * 4 + (threadIdx.x >> 6); // item = (b*NH + h)*L + l
  int lane = threadIdx.x & 63;
  int l = item % L;
  int bh = item / L;
  int h = bh % NH;
  int b = bh / NH;
  float x = in[(size_t)(b * L + l) * in_stride + in_off + h * DH + lane];
  float o;
  if (do_rope) {
    float ss = x * x;
#pragma unroll
    for (int m = 32; m > 0; m >>= 1) ss += __shfl_xor(ss, m, 64);
    float s = sqrtf(scale[h]);
    x *= s * rsqrtf(ss + 1e-6f);
    int j = lane < 24 ? lane : (lane < 48 ? lane - 24 : 0);
    int partner = lane < 24 ? lane + 24 : (lane < 48 ? lane - 24 : lane);
    float other = __shfl(x, partner, 64);
    if (lane < 48) {
      int c = j >> 3, f = j & 7;
      // ROPE_FREQS[h][f] = pi * 10^((f*12+h)/96)
      float fr = __expf(1.14472988584940017f +
                        (float)(f * 12 + h) * (2.30258509299404568f / 96.0f));
      float th = pos[(size_t)(b * L + l) * 3 + c] * fr;
      float st, ct;
      sincosf(th, &st, &ct);
      o = (lane < 24) ? (x * ct - other * st) : (x * ct + other * st);
    } else {
      o = x;
    }
  } else {
    o = x;
  }
  if (transpose)
    out[((size_t)bh * DH + lane) * L + l] = __float2bfloat16(o);
  else
    out[(size_t)item * DH + lane] = __float2bfloat16(o);
}

// ---------- MFMA flash attention, fixed-bound softmax ----------
// Q,K: (BH, L, DH) bf16; Vt: (BH, DH, L) bf16; O: (B, L, NH, DH) bf16
// Scores bounded: |s| <= scale[h] (cos-normalized q,k) -> fixed max, no running max.
// LDS: stride 64 bf16 (128B) + XOR-8 swizzle on 16B chunks -> <=2-way conflicts.
#define ASW(row, chunk) (((row) << 6) + ((((chunk) ^ ((row)&7))) << 3))
__global__ __launch_bounds__(256) void k_attn_mfma(const bf16* __restrict__ Q,
                                                   const bf16* __restrict__ K,
                                                   const bf16* __restrict__ Vt,
                                                   const float* __restrict__ scale,
                                                   bf16* __restrict__ O) {
  __shared__ __align__(16) bf16 Ks[64 * 64];
  __shared__ __align__(16) bf16 Vs[64 * 64];
  __shared__ __align__(16) bf16 Ps[64 * 64];
  int qt = blockIdx.x & 31, bh = blockIdx.x >> 5;
  int h = bh % NH;
  float smax = scale[h];
  int t = threadIdx.x, w = t >> 6, lane = t & 63;
  int quad = lane >> 4, l16 = lane & 15;
  int sr = t >> 3, sc = t & 7; // staging row/chunk (rows 0..31; +32 for half 1)

  const bf16* qrow = Q + ((size_t)(bh * L) + qt * 64 + w * 16 + l16) * DH;
  bfrag qf0 = *(const bfrag*)&qrow[quad * 8];
  bfrag qf1 = *(const bfrag*)&qrow[32 + quad * 8];

  ffrag o_acc[4];
#pragma unroll
  for (int j = 0; j < 4; j++) o_acc[j] = (ffrag){0.f, 0.f, 0.f, 0.f};
  float l_part[4] = {0.f, 0.f, 0.f, 0.f};

  const bf16* kbase = K + (size_t)(bh * L) * DH;
  const bf16* vbase = Vt + (size_t)bh * DH * L;

  for (int kt = 0; kt < 32; kt++) {
    int k0 = kt * 64;
    __syncthreads(); // prev iter reads of Ks/Vs done
#pragma unroll
    for (int half = 0; half < 2; half++) {
      int r = sr + half * 32;
      *(float4*)&Ks[ASW(r, sc)] = *(const float4*)&kbase[(size_t)(k0 + r) * DH + sc * 8];
      *(float4*)&Vs[ASW(r, sc)] = *(const float4*)&vbase[(size_t)r * L + k0 + sc * 8];
    }
    __syncthreads();
    // ---- S = Q K^T ----
    ffrag s_acc[4];
#pragma unroll
    for (int j = 0; j < 4; j++) {
      int r = j * 16 + l16;
      bfrag kf0 = *(const bfrag*)&Ks[ASW(r, quad)];
      bfrag kf1 = *(const bfrag*)&Ks[ASW(r, 4 + quad)];
      ffrag z = (ffrag){0.f, 0.f, 0.f, 0.f};
      z = __builtin_amdgcn_mfma_f32_16x16x32_bf16(qf0, kf0, z, 0, 0, 0);
      z = __builtin_amdgcn_mfma_f32_16x16x32_bf16(qf1, kf1, z, 0, 0, 0);
      s_acc[j] = z;
    }
    // ---- p = exp(s - smax); accumulate l in-lane; write P (wave-private rows) ----
#pragma unroll
    for (int j = 0; j < 4; j++) {
#pragma unroll
      for (int reg = 0; reg < 4; reg++) {
        float p = __expf(s_acc[j][reg] - smax);
        l_part[reg] += p;
        int q = w * 16 + quad * 4 + reg;
        int key = j * 16 + l16;
        Ps[(q << 6) + ((((key >> 3) ^ (q & 7))) << 3) + (key & 7)] = __float2bfloat16(p);
      }
    }
    // ---- O += P V (in-wave RAW on Ps: DS ordering suffices, no barrier) ----
    int qr = w * 16 + l16;
    bfrag pf0 = *(const bfrag*)&Ps[ASW(qr, quad)];
    bfrag pf1 = *(const bfrag*)&Ps[ASW(qr, 4 + quad)];
#pragma unroll
    for (int jd = 0; jd < 4; jd++) {
      int r = jd * 16 + l16;
      bfrag vf0 = *(const bfrag*)&Vs[ASW(r, quad)];
      bfrag vf1 = *(const bfrag*)&Vs[ASW(r, 4 + quad)];
      o_acc[jd] = __builtin_amdgcn_mfma_f32_16x16x32_bf16(pf0, vf0, o_acc[jd], 0, 0, 0);
      o_acc[jd] = __builtin_amdgcn_mfma_f32_16x16x32_bf16(pf1, vf1, o_acc[jd], 0, 0, 0);
    }
  }
  // ---- final l reduction over the 16 key-lanes (once) ----
#pragma unroll
  for (int reg = 0; reg < 4; reg++) {
#pragma unroll
    for (int msk = 1; msk < 16; msk <<= 1) l_part[reg] += __shfl_xor(l_part[reg], msk, 64);
  }
  // ---- epilogue: normalize + store (B,L,NH,DH) bf16 ----
  int b = bh / NH;
#pragma unroll
  for (int reg = 0; reg < 4; reg++) {
    float inv = 1.f / l_part[reg];
    int l = qt * 64 + w * 16 + quad * 4 + reg;
#pragma unroll
    for (int jd = 0; jd < 4; jd++) {
      int d = jd * 16 + l16;
      O[(((size_t)b * L + l) * NH + h) * DH + d] = __float2bfloat16(o_acc[jd][reg] * inv);
    }
  }
}

// ---------- SwiGLU: out[m,j] = a * silu(g), bf16 out, float4 vectorized ----------
__global__ void k_ffact(const float* __restrict__ U, bf16* __restrict__ Out) {
  int idx = blockIdx.x * blockDim.x + threadIdx.x;
  int total = M_TOK * (DFF / 4);
  if (idx >= total) return;
  int mrow = idx / (DFF / 4), c = idx % (DFF / 4);
  const float* rowp = U + (size_t)mrow * (2 * DFF);
  float4 a = *(const float4*)&rowp[c * 4];
  float4 g = *(const float4*)&rowp[DFF + c * 4];
  float r0 = a.x * g.x / (1.f + __expf(-g.x));
  float r1 = a.y * g.y / (1.f + __expf(-g.y));
  float r2 = a.z * g.z / (1.f + __expf(-g.z));
  float r3 = a.w * g.w / (1.f + __expf(-g.w));
  bf16* o = Out + (size_t)mrow * DFF + c * 4;
  o[0] = __float2bfloat16(r0);
  o[1] = __float2bfloat16(r1);
  o[2] = __float2bfloat16(r2);
  o[3] = __float2bfloat16(r3);
}

extern "C" void kernel_launch(void* const* d_in, const int* in_sizes, int n_in,
                              void* d_out, int out_size, void* d_ws, size_t ws_size,
                              hipStream_t stream) {
  const float* x = (const float*)d_in[0];
  const float* pos = (const float*)d_in[1];
  const float* x_cross = (const float*)d_in[2];
  const float* pos_cross = (const float*)d_in[3];
  const float* sa_norm_scale = (const float*)d_in[4];
  const float* sa_wqkv = (const float*)d_in[5];
  const float* sa_scale = (const float*)d_in[6];
  const float* sa_wout = (const float*)d_in[7];
  const float* ca_norm_scale = (const float*)d_in[8];
  const float* ca_norm_cross_scale = (const float*)d_in[9];
  const float* ca_wq = (const float*)d_in[10];
  const float* ca_wkv = (const float*)d_in[11];
  const float* ca_scale = (const float*)d_in[12];
  const float* ca_wout = (const float*)d_in[13];
  const float* ff_norm_scale = (const float*)d_in[14];
  const float* ff_wup = (const float*)d_in[15];
  const float* ff_wdown = (const float*)d_in[16];
  float* out = (float*)d_out;

  float* ws = (float*)d_ws;
  const size_t S = (size_t)M_TOK * DM; // 3,145,728
  float* xbuf = ws;             // S : running residual (f32)
  float* bigbuf = ws + S;       // 6S f32: qkv / kv+caq / ff-up
  float* caq = bigbuf + 2 * S;  // ca q-proj out (f32, S) while kv in bigbuf[0,2S)
  bf16* b16 = (bf16*)(ws + 7 * S);
  bf16* qb = b16;               // (BH, L, DH)
  bf16* kb = b16 + S;           // (BH, L, DH)
  bf16* vtb = b16 + 2 * S;      // (BH, DH, L)
  bf16* hb = b16 + 3 * S;
  bf16* hcb = b16 + 4 * S;
  bf16* obb = b16 + 5 * S;      // attn out (B,L,NH,DH)
  bf16* wqkvb = b16 + 6 * S;
  bf16* woutb = wqkvb + (size_t)3 * DM * DM;
  bf16* wqb = woutb + (size_t)DM * DM;
  bf16* wkvb = wqb + (size_t)DM * DM;
  bf16* wout2b = wkvb + (size_t)2 * DM * DM;
  bf16* wupb = wout2b + (size_t)DM * DM;
  bf16* wdownb = wupb + (size_t)2 * DFF * DM;
  bf16* ffb = b16;              // aliases qb/kb/vtb (dead in FF phase), 3S bf16

  const int ropeGrid = B * NH * L / 4;
  const int attnGrid = B * NH * (L / 64); // 768

#define CAST(src, dst, n) k_castw<<<((n) + 255) / 256, 256, 0, stream>>>(src, dst, n)
  CAST(sa_wqkv, wqkvb, 3 * DM * DM);
  CAST(sa_wout, woutb, DM * DM);
  CAST(ca_wq, wqb, DM * DM);
  CAST(ca_wkv, wkvb, 2 * DM * DM);
  CAST(ca_wout, wout2b, DM * DM);
  CAST(ff_wup, wupb, 2 * DFF * DM);
  CAST(ff_wdown, wdownb, DM * DFF);
#undef CAST

  // ---- prologue: residual init + cross norm ----
  hipMemcpyAsync(xbuf, x, S * sizeof(float), hipMemcpyDeviceToDevice, stream);
  k_rmsnorm<<<M_TOK, 256, 0, stream>>>(x_cross, ca_norm_cross_scale, hcb);

  // ---- self attention ----
  k_rmsnorm<<<M_TOK, 256, 0, stream>>>(xbuf, sa_norm_scale, hb);
  k_gemm_mfma<<<dim3(3 * DM / 128, M_TOK / 128), 256, 0, stream>>>(
      hb, wqkvb, bigbuf, nullptr, M_TOK, 3 * DM, DM);
  k_rope_cs<<<ropeGrid, 256, 0, stream>>>(bigbuf, 3 * DM, 0, pos, sa_scale, qb, 1, 0);
  k_rope_cs<<<ropeGrid, 256, 0, stream>>>(bigbuf, 3 * DM, DM, pos, sa_scale, kb, 1, 0);
  k_rope_cs<<<ropeGrid, 256, 0, stream>>>(bigbuf, 3 * DM, 2 * DM, nullptr, nullptr, vtb, 0, 1);
  k_attn_mfma<<<attnGrid, 256, 0, stream>>>(qb, kb, vtb, sa_scale, obb);
  k_gemm_mfma<<<dim3(DM / 128, M_TOK / 128), 256, 0, stream>>>(
      obb, woutb, xbuf, xbuf, M_TOK, DM, DM);

  // ---- cross attention ----
  k_rmsnorm<<<M_TOK, 256, 0, stream>>>(xbuf, ca_norm_scale, hb);
  k_gemm_mfma<<<dim3(DM / 128, M_TOK / 128), 256, 0, stream>>>(
      hb, wqb, caq, nullptr, M_TOK, DM, DM);
  k_gemm_mfma<<<dim3(2 * DM / 128, M_TOK / 128), 256, 0, stream>>>(
      hcb, wkvb, bigbuf, nullptr, M_TOK, 2 * DM, DM);
  k_rope_cs<<<ropeGrid, 256, 0, stream>>>(caq, DM, 0, pos, ca_scale, qb, 1, 0);
  k_rope_cs<<<ropeGrid, 256, 0, stream>>>(bigbuf, 2 * DM, 0, pos_cross, ca_scale, kb, 1, 0);
  k_rope_cs<<<ropeGrid, 256, 0, stream>>>(bigbuf, 2 * DM, DM, nullptr, nullptr, vtb, 0, 1);
  k_attn_mfma<<<attnGrid, 256, 0, stream>>>(qb, kb, vtb, ca_scale, obb);
  k_gemm_mfma<<<dim3(DM / 128, M_TOK / 128), 256, 0, stream>>>(
      obb, wout2b, xbuf, xbuf, M_TOK, DM, DM);

  // ---- feed-forward ----
  k_rmsnorm<<<M_TOK, 256, 0, stream>>>(xbuf, ff_norm_scale, hb);
  k_gemm_mfma<<<dim3(2 * DFF / 128, M_TOK / 128), 256, 0, stream>>>(
      hb, wupb, bigbuf, nullptr, M_TOK, 2 * DFF, DM);
  const int nFF4 = M_TOK * DFF / 4;
  k_ffact<<<(nFF4 + 255) / 256, 256, 0, stream>>>(bigbuf, ffb);
  k_gemm_mfma<<<dim3(DM / 128, M_TOK / 128), 256, 0, stream>>>(
      ffb, wdownb, out, xbuf, M_TOK, DM, DFF);
}

// Round 7
// 570.164 us; speedup vs baseline: 19.6925x; 1.1382x over previous
//
#include <hip/hip_runtime.h>
#include <hip/hip_bf16.h>
#include <math.h>

typedef __hip_bfloat16 bf16;

#define B 2
#define L 2048
#define DM 768
#define NH 12
#define DH 64
#define DFF 2304
#define M_TOK (B * L) // 4096

typedef __attribute__((ext_vector_type(8))) short bfrag;
typedef __attribute__((ext_vector_type(4))) float ffrag;

__device__ __forceinline__ float waveSum(float v) {
#pragma unroll
  for (int o = 32; o > 0; o >>= 1) v += __shfl_down(v, o, 64);
  return v;
}

__device__ __forceinline__ void gld16(void* l, const void* g) {
  __builtin_amdgcn_global_load_lds((const __attribute__((address_space(1))) unsigned*)g,
                                   (__attribute__((address_space(3))) unsigned*)l, 16, 0, 0);
}

// ---------- weight cast fp32 -> bf16 ----------
__global__ void k_castw(const float* __restrict__ in, bf16* __restrict__ out, int n) {
  int i = blockIdx.x * blockDim.x + threadIdx.x;
  if (i < n) out[i] = __float2bfloat16(in[i]);
}

// ---------- RMSNorm: one block (256 thr) per row of 768; bf16 out ----------
__global__ __launch_bounds__(256) void k_rmsnorm(const float* __restrict__ in,
                                                 const float* __restrict__ scale,
                                                 bf16* __restrict__ out) {
  int row = blockIdx.x;
  int t = threadIdx.x;
  const float* r = in + (size_t)row * DM;
  float x0 = r[t], x1 = r[t + 256], x2 = r[t + 512];
  float ss = x0 * x0 + x1 * x1 + x2 * x2;
  ss = waveSum(ss);
  __shared__ float red[4];
  int w = t >> 6, ln = t & 63;
  if (ln == 0) red[w] = ss;
  __syncthreads();
  float tot = red[0] + red[1] + red[2] + red[3];
  float g = rsqrtf(tot / (float)DM + 1e-6f);
  bf16* o = out + (size_t)row * DM;
  o[t] = __float2bfloat16(x0 * g * scale[t]);
  o[t + 256] = __float2bfloat16(x1 * g * scale[t + 256]);
  o[t + 512] = __float2bfloat16(x2 * g * scale[t + 512]);
}

// ---------- MFMA GEMM: 128 x NT tile; OBF=1 -> bf16 out (no res), else f32 (+res) ----------
template <int NT, int OBF>
__global__ __launch_bounds__(256) void k_gemm(const bf16* __restrict__ A,
                                              const bf16* __restrict__ W,
                                              float* __restrict__ C,
                                              bf16* __restrict__ Cb,
                                              const float* __restrict__ res,
                                              int M, int N, int K) {
  __shared__ __align__(16) bf16 As[128 * 32];
  __shared__ __align__(16) bf16 Bs[NT * 32];
  const int t = threadIdx.x;
  const int w = t >> 6, lane = t & 63;
  const int m0 = blockIdx.y * 128, n0 = blockIdx.x * NT;
  const int quad = lane >> 4, l16 = lane & 15;
  constexpr int MI = (NT == 128) ? 4 : 2;
  const int wrow = (NT == 128) ? (w >> 1) * 64 : w * 32;
  const int wcol = (NT == 128) ? (w & 1) * 64 : 0;

  ffrag acc[MI][4];
#pragma unroll
  for (int i = 0; i < MI; i++)
#pragma unroll
    for (int j = 0; j < 4; j++) acc[i][j] = (ffrag){0.f, 0.f, 0.f, 0.f};

  for (int k0 = 0; k0 < K; k0 += 32) {
#pragma unroll
    for (int it = 0; it < 2; it++) {
      int lc = (w * 2 + it) * 64 + lane;
      int row = lc >> 2;
      int kc = (lc & 3) ^ ((row >> 1) & 3);
      gld16(&As[lc * 8], &A[(size_t)(m0 + row) * K + k0 + kc * 8]);
    }
    if (NT == 128) {
#pragma unroll
      for (int it = 0; it < 2; it++) {
        int lc = (w * 2 + it) * 64 + lane;
        int row = lc >> 2;
        int kc = (lc & 3) ^ ((row >> 1) & 3);
        gld16(&Bs[lc * 8], &W[(size_t)(n0 + row) * K + k0 + kc * 8]);
      }
    } else {
      int lc = w * 64 + lane;
      int row = lc >> 2;
      int kc = (lc & 3) ^ ((row >> 1) & 3);
      gld16(&Bs[lc * 8], &W[(size_t)(n0 + row) * K + k0 + kc * 8]);
    }
    __syncthreads();
    bfrag af[MI], bfv[4];
#pragma unroll
    for (int i = 0; i < MI; i++) {
      int r = wrow + i * 16 + l16;
      af[i] = *(const bfrag*)&As[r * 32 + (quad ^ ((r >> 1) & 3)) * 8];
    }
#pragma unroll
    for (int j = 0; j < 4; j++) {
      int r = wcol + j * 16 + l16;
      bfv[j] = *(const bfrag*)&Bs[r * 32 + (quad ^ ((r >> 1) & 3)) * 8];
    }
#pragma unroll
    for (int i = 0; i < MI; i++)
#pragma unroll
      for (int j = 0; j < 4; j++)
        acc[i][j] = __builtin_amdgcn_mfma_f32_16x16x32_bf16(af[i], bfv[j], acc[i][j], 0, 0, 0);
    __syncthreads();
  }
#pragma unroll
  for (int i = 0; i < MI; i++) {
    int mrow = m0 + wrow + i * 16 + quad * 4;
#pragma unroll
    for (int j = 0; j < 4; j++) {
      int ncol = n0 + wcol + j * 16 + l16;
#pragma unroll
      for (int r = 0; r < 4; r++) {
        float v = acc[i][j][r];
        size_t idx = (size_t)(mrow + r) * N + ncol;
        if (OBF) {
          Cb[idx] = __float2bfloat16(v);
        } else {
          if (res) v += res[idx];
          C[idx] = v;
        }
      }
    }
  }
}

// ---------- fused ff_up + SwiGLU: Out(M x DFF, bf16) = a * silu(g) ----------
// block: 128 rows x 64 cols; a-cols from Wup rows [n0,n0+64), g from [DFF+n0,+64)
__global__ __launch_bounds__(256) void k_ffup(const bf16* __restrict__ A,
                                              const bf16* __restrict__ Wup,
                                              bf16* __restrict__ Out) {
  __shared__ __align__(16) bf16 As[128 * 32];
  __shared__ __align__(16) bf16 Ba[64 * 32];
  __shared__ __align__(16) bf16 Bg[64 * 32];
  const int t = threadIdx.x, w = t >> 6, lane = t & 63;
  const int m0 = blockIdx.y * 128, n0 = blockIdx.x * 64;
  const int quad = lane >> 4, l16 = lane & 15;

  ffrag aa[2][4], ag[2][4];
#pragma unroll
  for (int i = 0; i < 2; i++)
#pragma unroll
    for (int j = 0; j < 4; j++) {
      aa[i][j] = (ffrag){0.f, 0.f, 0.f, 0.f};
      ag[i][j] = (ffrag){0.f, 0.f, 0.f, 0.f};
    }

  for (int k0 = 0; k0 < DM; k0 += 32) {
#pragma unroll
    for (int it = 0; it < 2; it++) {
      int lc = (w * 2 + it) * 64 + lane;
      int row = lc >> 2;
      int kc = (lc & 3) ^ ((row >> 1) & 3);
      gld16(&As[lc * 8], &A[(size_t)(m0 + row) * DM + k0 + kc * 8]);
    }
    {
      int lc = w * 64 + lane;
      int row = lc >> 2;
      int kc = (lc & 3) ^ ((row >> 1) & 3);
      gld16(&Ba[lc * 8], &Wup[(size_t)(n0 + row) * DM + k0 + kc * 8]);
      gld16(&Bg[lc * 8], &Wup[(size_t)(DFF + n0 + row) * DM + k0 + kc * 8]);
    }
    __syncthreads();
    bfrag af[2], ba[4], bg[4];
#pragma unroll
    for (int i = 0; i < 2; i++) {
      int r = w * 32 + i * 16 + l16;
      af[i] = *(const bfrag*)&As[r * 32 + (quad ^ ((r >> 1) & 3)) * 8];
    }
#pragma unroll
    for (int j = 0; j < 4; j++) {
      int r = j * 16 + l16;
      int sw = (quad ^ ((r >> 1) & 3)) * 8;
      ba[j] = *(const bfrag*)&Ba[r * 32 + sw];
      bg[j] = *(const bfrag*)&Bg[r * 32 + sw];
    }
#pragma unroll
    for (int i = 0; i < 2; i++)
#pragma unroll
      for (int j = 0; j < 4; j++) {
        aa[i][j] = __builtin_amdgcn_mfma_f32_16x16x32_bf16(af[i], ba[j], aa[i][j], 0, 0, 0);
        ag[i][j] = __builtin_amdgcn_mfma_f32_16x16x32_bf16(af[i], bg[j], ag[i][j], 0, 0, 0);
      }
    __syncthreads();
  }
#pragma unroll
  for (int i = 0; i < 2; i++) {
    int mrow = m0 + w * 32 + i * 16 + quad * 4;
#pragma unroll
    for (int j = 0; j < 4; j++) {
      int ncol = n0 + j * 16 + l16;
#pragma unroll
      for (int r = 0; r < 4; r++) {
        float a = aa[i][j][r], g = ag[i][j][r];
        float v = a * g / (1.f + __expf(-g));
        Out[(size_t)(mrow + r) * DFF + ncol] = __float2bfloat16(v);
      }
    }
  }
}

// ---------- cos-scale + RoPE; one wave per (b,h,l); bf16 in/out ----------
// transpose=0: out (bh, L, DH)  [Q, K]
// transpose=1: out (bh, DH, L)  [V for PV B-operand]
__global__ __launch_bounds__(256) void k_rope_cs(const bf16* __restrict__ in, int in_stride,
                                                 int in_off, const float* __restrict__ pos,
                                                 const float* __restrict__ scale,
                                                 bf16* __restrict__ out, int do_rope,
                                                 int transpose) {
  int item = blockIdx.x * 4 + (threadIdx.x >> 6); // item = (b*NH + h)*L + l
  int lane = threadIdx.x & 63;
  int l = item % L;
  int bh = item / L;
  int h = bh % NH;
  int b = bh / NH;
  float x = __bfloat162float(in[(size_t)(b * L + l) * in_stride + in_off + h * DH + lane]);
  float o;
  if (do_rope) {
    float ss = x * x;
#pragma unroll
    for (int m = 32; m > 0; m >>= 1) ss += __shfl_xor(ss, m, 64);
    float s = sqrtf(scale[h]);
    x *= s * rsqrtf(ss + 1e-6f);
    int j = lane < 24 ? lane : (lane < 48 ? lane - 24 : 0);
    int partner = lane < 24 ? lane + 24 : (lane < 48 ? lane - 24 : lane);
    float other = __shfl(x, partner, 64);
    if (lane < 48) {
      int c = j >> 3, f = j & 7;
      // ROPE_FREQS[h][f] = pi * 10^((f*12+h)/96)
      float fr = __expf(1.14472988584940017f +
                        (float)(f * 12 + h) * (2.30258509299404568f / 96.0f));
      float th = pos[(size_t)(b * L + l) * 3 + c] * fr;
      float st, ct;
      sincosf(th, &st, &ct);
      o = (lane < 24) ? (x * ct - other * st) : (x * ct + other * st);
    } else {
      o = x;
    }
  } else {
    o = x;
  }
  if (transpose)
    out[((size_t)bh * DH + lane) * L + l] = __float2bfloat16(o);
  else
    out[(size_t)item * DH + lane] = __float2bfloat16(o);
}

// ---------- MFMA flash attention, fixed-bound softmax ----------
// Q,K: (BH, L, DH) bf16; Vt: (BH, DH, L) bf16; O: (B, L, NH, DH) bf16
#define ASW(row, chunk) (((row) << 6) + ((((chunk) ^ ((row)&7))) << 3))
__global__ __launch_bounds__(256) void k_attn_mfma(const bf16* __restrict__ Q,
                                                   const bf16* __restrict__ K,
                                                   const bf16* __restrict__ Vt,
                                                   const float* __restrict__ scale,
                                                   bf16* __restrict__ O) {
  __shared__ __align__(16) bf16 Ks[64 * 64];
  __shared__ __align__(16) bf16 Vs[64 * 64];
  __shared__ __align__(16) bf16 Ps[64 * 64];
  int qt = blockIdx.x & 31, bh = blockIdx.x >> 5;
  int h = bh % NH;
  float smax = scale[h];
  int t = threadIdx.x, w = t >> 6, lane = t & 63;
  int quad = lane >> 4, l16 = lane & 15;
  int sr = t >> 3, sc = t & 7;

  const bf16* qrow = Q + ((size_t)(bh * L) + qt * 64 + w * 16 + l16) * DH;
  bfrag qf0 = *(const bfrag*)&qrow[quad * 8];
  bfrag qf1 = *(const bfrag*)&qrow[32 + quad * 8];

  ffrag o_acc[4];
#pragma unroll
  for (int j = 0; j < 4; j++) o_acc[j] = (ffrag){0.f, 0.f, 0.f, 0.f};
  float l_part[4] = {0.f, 0.f, 0.f, 0.f};

  const bf16* kbase = K + (size_t)(bh * L) * DH;
  const bf16* vbase = Vt + (size_t)bh * DH * L;

  for (int kt = 0; kt < 32; kt++) {
    int k0 = kt * 64;
    __syncthreads();
#pragma unroll
    for (int half = 0; half < 2; half++) {
      int r = sr + half * 32;
      *(float4*)&Ks[ASW(r, sc)] = *(const float4*)&kbase[(size_t)(k0 + r) * DH + sc * 8];
      *(float4*)&Vs[ASW(r, sc)] = *(const float4*)&vbase[(size_t)r * L + k0 + sc * 8];
    }
    __syncthreads();
    ffrag s_acc[4];
#pragma unroll
    for (int j = 0; j < 4; j++) {
      int r = j * 16 + l16;
      bfrag kf0 = *(const bfrag*)&Ks[ASW(r, quad)];
      bfrag kf1 = *(const bfrag*)&Ks[ASW(r, 4 + quad)];
      ffrag z = (ffrag){0.f, 0.f, 0.f, 0.f};
      z = __builtin_amdgcn_mfma_f32_16x16x32_bf16(qf0, kf0, z, 0, 0, 0);
      z = __builtin_amdgcn_mfma_f32_16x16x32_bf16(qf1, kf1, z, 0, 0, 0);
      s_acc[j] = z;
    }
#pragma unroll
    for (int j = 0; j < 4; j++) {
#pragma unroll
      for (int reg = 0; reg < 4; reg++) {
        float p = __expf(s_acc[j][reg] - smax);
        l_part[reg] += p;
        int q = w * 16 + quad * 4 + reg;
        int key = j * 16 + l16;
        Ps[(q << 6) + ((((key >> 3) ^ (q & 7))) << 3) + (key & 7)] = __float2bfloat16(p);
      }
    }
    int qr = w * 16 + l16;
    bfrag pf0 = *(const bfrag*)&Ps[ASW(qr, quad)];
    bfrag pf1 = *(const bfrag*)&Ps[ASW(qr, 4 + quad)];
#pragma unroll
    for (int jd = 0; jd < 4; jd++) {
      int r = jd * 16 + l16;
      bfrag vf0 = *(const bfrag*)&Vs[ASW(r, quad)];
      bfrag vf1 = *(const bfrag*)&Vs[ASW(r, 4 + quad)];
      o_acc[jd] = __builtin_amdgcn_mfma_f32_16x16x32_bf16(pf0, vf0, o_acc[jd], 0, 0, 0);
      o_acc[jd] = __builtin_amdgcn_mfma_f32_16x16x32_bf16(pf1, vf1, o_acc[jd], 0, 0, 0);
    }
  }
#pragma unroll
  for (int reg = 0; reg < 4; reg++) {
#pragma unroll
    for (int msk = 1; msk < 16; msk <<= 1) l_part[reg] += __shfl_xor(l_part[reg], msk, 64);
  }
  int b = bh / NH;
#pragma unroll
  for (int reg = 0; reg < 4; reg++) {
    float inv = 1.f / l_part[reg];
    int l = qt * 64 + w * 16 + quad * 4 + reg;
#pragma unroll
    for (int jd = 0; jd < 4; jd++) {
      int d = jd * 16 + l16;
      O[(((size_t)b * L + l) * NH + h) * DH + d] = __float2bfloat16(o_acc[jd][reg] * inv);
    }
  }
}

extern "C" void kernel_launch(void* const* d_in, const int* in_sizes, int n_in,
                              void* d_out, int out_size, void* d_ws, size_t ws_size,
                              hipStream_t stream) {
  const float* x = (const float*)d_in[0];
  const float* pos = (const float*)d_in[1];
  const float* x_cross = (const float*)d_in[2];
  const float* pos_cross = (const float*)d_in[3];
  const float* sa_norm_scale = (const float*)d_in[4];
  const float* sa_wqkv = (const float*)d_in[5];
  const float* sa_scale = (const float*)d_in[6];
  const float* sa_wout = (const float*)d_in[7];
  const float* ca_norm_scale = (const float*)d_in[8];
  const float* ca_norm_cross_scale = (const float*)d_in[9];
  const float* ca_wq = (const float*)d_in[10];
  const float* ca_wkv = (const float*)d_in[11];
  const float* ca_scale = (const float*)d_in[12];
  const float* ca_wout = (const float*)d_in[13];
  const float* ff_norm_scale = (const float*)d_in[14];
  const float* ff_wup = (const float*)d_in[15];
  const float* ff_wdown = (const float*)d_in[16];
  float* out = (float*)d_out;

  float* ws = (float*)d_ws;
  const size_t S = (size_t)M_TOK * DM; // 3,145,728
  float* xbuf = ws; // S f32: running residual
  bf16* b16 = (bf16*)(ws + S);
  bf16* qkvb = b16;             // 3S: qkv proj (self) / caq+cakv (cross) / ffact (FF)
  bf16* qb = b16 + 3 * S;       // (BH, L, DH)
  bf16* kb = b16 + 4 * S;       // (BH, L, DH)
  bf16* vtb = b16 + 5 * S;      // (BH, DH, L)
  bf16* hb = b16 + 6 * S;
  bf16* hcb = b16 + 7 * S;
  bf16* obb = b16 + 8 * S;      // attn out (B,L,NH,DH)
  bf16* wqkvb = b16 + 9 * S;
  bf16* woutb = wqkvb + (size_t)3 * DM * DM;
  bf16* wqb = woutb + (size_t)DM * DM;
  bf16* wkvb = wqb + (size_t)DM * DM;
  bf16* wout2b = wkvb + (size_t)2 * DM * DM;
  bf16* wupb = wout2b + (size_t)DM * DM;
  bf16* wdownb = wupb + (size_t)2 * DFF * DM;
  bf16* ffb = qkvb; // 3S bf16, dead after cross-attn rope

  const int ropeGrid = B * NH * L / 4;
  const int attnGrid = B * NH * (L / 64); // 768

#define CAST(src, dst, n) k_castw<<<((n) + 255) / 256, 256, 0, stream>>>(src, dst, n)
  CAST(sa_wqkv, wqkvb, 3 * DM * DM);
  CAST(sa_wout, woutb, DM * DM);
  CAST(ca_wq, wqb, DM * DM);
  CAST(ca_wkv, wkvb, 2 * DM * DM);
  CAST(ca_wout, wout2b, DM * DM);
  CAST(ff_wup, wupb, 2 * DFF * DM);
  CAST(ff_wdown, wdownb, DM * DFF);
#undef CAST

  // ---- prologue: cross norm ----
  k_rmsnorm<<<M_TOK, 256, 0, stream>>>(x_cross, ca_norm_cross_scale, hcb);

  // ---- self attention ----
  k_rmsnorm<<<M_TOK, 256, 0, stream>>>(x, sa_norm_scale, hb);
  k_gemm<128, 1><<<dim3(3 * DM / 128, M_TOK / 128), 256, 0, stream>>>(
      hb, wqkvb, nullptr, qkvb, nullptr, M_TOK, 3 * DM, DM);
  k_rope_cs<<<ropeGrid, 256, 0, stream>>>(qkvb, 3 * DM, 0, pos, sa_scale, qb, 1, 0);
  k_rope_cs<<<ropeGrid, 256, 0, stream>>>(qkvb, 3 * DM, DM, pos, sa_scale, kb, 1, 0);
  k_rope_cs<<<ropeGrid, 256, 0, stream>>>(qkvb, 3 * DM, 2 * DM, nullptr, nullptr, vtb, 0, 1);
  k_attn_mfma<<<attnGrid, 256, 0, stream>>>(qb, kb, vtb, sa_scale, obb);
  k_gemm<64, 0><<<dim3(DM / 64, M_TOK / 128), 256, 0, stream>>>(
      obb, woutb, xbuf, nullptr, x, M_TOK, DM, DM); // xbuf = attn@wout + x

  // ---- cross attention ----
  k_rmsnorm<<<M_TOK, 256, 0, stream>>>(xbuf, ca_norm_scale, hb);
  k_gemm<64, 1><<<dim3(DM / 64, M_TOK / 128), 256, 0, stream>>>(
      hb, wqb, nullptr, qkvb, nullptr, M_TOK, DM, DM);
  k_gemm<128, 1><<<dim3(2 * DM / 128, M_TOK / 128), 256, 0, stream>>>(
      hcb, wkvb, nullptr, qkvb + S, nullptr, M_TOK, 2 * DM, DM);
  k_rope_cs<<<ropeGrid, 256, 0, stream>>>(qkvb, DM, 0, pos, ca_scale, qb, 1, 0);
  k_rope_cs<<<ropeGrid, 256, 0, stream>>>(qkvb + S, 2 * DM, 0, pos_cross, ca_scale, kb, 1, 0);
  k_rope_cs<<<ropeGrid, 256, 0, stream>>>(qkvb + S, 2 * DM, DM, nullptr, nullptr, vtb, 0, 1);
  k_attn_mfma<<<attnGrid, 256, 0, stream>>>(qb, kb, vtb, ca_scale, obb);
  k_gemm<64, 0><<<dim3(DM / 64, M_TOK / 128), 256, 0, stream>>>(
      obb, wout2b, xbuf, nullptr, xbuf, M_TOK, DM, DM);

  // ---- feed-forward (fused up+SwiGLU, then down) ----
  k_rmsnorm<<<M_TOK, 256, 0, stream>>>(xbuf, ff_norm_scale, hb);
  k_ffup<<<dim3(DFF / 64, M_TOK / 128), 256, 0, stream>>>(hb, wupb, ffb);
  k_gemm<64, 0><<<dim3(DM / 64, M_TOK / 128), 256, 0, stream>>>(
      ffb, wdownb, out, nullptr, xbuf, M_TOK, DM, DFF);
}

// Round 8
// 489.977 us; speedup vs baseline: 22.9153x; 1.1637x over previous
//
#include <hip/hip_runtime.h>
#include <hip/hip_bf16.h>
#include <math.h>

typedef __hip_bfloat16 bf16;

#define B 2
#define L 2048
#define DM 768
#define NH 12
#define DH 64
#define DFF 2304
#define M_TOK (B * L) // 4096

typedef __attribute__((ext_vector_type(8))) short bfrag;
typedef __attribute__((ext_vector_type(4))) float ffrag;
typedef __attribute__((ext_vector_type(16))) float facc16;

__device__ __forceinline__ float waveSum(float v) {
#pragma unroll
  for (int o = 32; o > 0; o >>= 1) v += __shfl_down(v, o, 64);
  return v;
}

__device__ __forceinline__ void gld16(void* l, const void* g) {
  __builtin_amdgcn_global_load_lds((const __attribute__((address_space(1))) unsigned*)g,
                                   (__attribute__((address_space(3))) unsigned*)l, 16, 0, 0);
}

// element-index swizzle for 64-col bf16 LDS tiles (16B chunk XOR row&7)
#define ASW(row, chunk) (((row) << 6) + ((((chunk) ^ ((row)&7))) << 3))

// ---------- fused weight cast fp32 -> bf16 (7 segments, contiguous dst arena) ----------
__global__ void k_castall(const float* __restrict__ s0, const float* __restrict__ s1,
                          const float* __restrict__ s2, const float* __restrict__ s3,
                          const float* __restrict__ s4, const float* __restrict__ s5,
                          const float* __restrict__ s6, bf16* __restrict__ dst) {
  const size_t DM2 = (size_t)DM * DM;
  size_t u = ((size_t)blockIdx.x * 256 + threadIdx.x) * 4;
  if (u >= 17 * DM2) return;
  const float* src;
  size_t loc;
  if (u < 3 * DM2) { src = s0; loc = u; }
  else if (u < 4 * DM2) { src = s1; loc = u - 3 * DM2; }
  else if (u < 5 * DM2) { src = s2; loc = u - 4 * DM2; }
  else if (u < 7 * DM2) { src = s3; loc = u - 5 * DM2; }
  else if (u < 8 * DM2) { src = s4; loc = u - 7 * DM2; }
  else if (u < 14 * DM2) { src = s5; loc = u - 8 * DM2; }
  else { src = s6; loc = u - 14 * DM2; }
  float4 v = *(const float4*)&src[loc];
  bf16* d = dst + u;
  d[0] = __float2bfloat16(v.x);
  d[1] = __float2bfloat16(v.y);
  d[2] = __float2bfloat16(v.z);
  d[3] = __float2bfloat16(v.w);
}

// ---------- RMSNorm: one block (256 thr) per row of 768; bf16 out ----------
__global__ __launch_bounds__(256) void k_rmsnorm(const float* __restrict__ in,
                                                 const float* __restrict__ scale,
                                                 bf16* __restrict__ out) {
  int row = blockIdx.x;
  int t = threadIdx.x;
  const float* r = in + (size_t)row * DM;
  float x0 = r[t], x1 = r[t + 256], x2 = r[t + 512];
  float ss = x0 * x0 + x1 * x1 + x2 * x2;
  ss = waveSum(ss);
  __shared__ float red[4];
  int w = t >> 6, ln = t & 63;
  if (ln == 0) red[w] = ss;
  __syncthreads();
  float tot = red[0] + red[1] + red[2] + red[3];
  float g = rsqrtf(tot / (float)DM + 1e-6f);
  bf16* o = out + (size_t)row * DM;
  o[t] = __float2bfloat16(x0 * g * scale[t]);
  o[t + 256] = __float2bfloat16(x1 * g * scale[t + 256]);
  o[t + 512] = __float2bfloat16(x2 * g * scale[t + 512]);
}

// ---------- MFMA GEMM: 128 x NT tile; OBF=1 -> bf16 out (no res), else f32 (+res) ----------
template <int NT, int OBF>
__global__ __launch_bounds__(256) void k_gemm(const bf16* __restrict__ A,
                                              const bf16* __restrict__ W,
                                              float* __restrict__ C,
                                              bf16* __restrict__ Cb,
                                              const float* __restrict__ res,
                                              int M, int N, int K) {
  __shared__ __align__(16) bf16 As[128 * 32];
  __shared__ __align__(16) bf16 Bs[NT * 32];
  const int t = threadIdx.x;
  const int w = t >> 6, lane = t & 63;
  const int m0 = blockIdx.y * 128, n0 = blockIdx.x * NT;
  const int quad = lane >> 4, l16 = lane & 15;
  constexpr int MI = (NT == 128) ? 4 : 2;
  const int wrow = (NT == 128) ? (w >> 1) * 64 : w * 32;
  const int wcol = (NT == 128) ? (w & 1) * 64 : 0;

  ffrag acc[MI][4];
#pragma unroll
  for (int i = 0; i < MI; i++)
#pragma unroll
    for (int j = 0; j < 4; j++) acc[i][j] = (ffrag){0.f, 0.f, 0.f, 0.f};

  for (int k0 = 0; k0 < K; k0 += 32) {
#pragma unroll
    for (int it = 0; it < 2; it++) {
      int lc = (w * 2 + it) * 64 + lane;
      int row = lc >> 2;
      int kc = (lc & 3) ^ ((row >> 1) & 3);
      gld16(&As[lc * 8], &A[(size_t)(m0 + row) * K + k0 + kc * 8]);
    }
    if (NT == 128) {
#pragma unroll
      for (int it = 0; it < 2; it++) {
        int lc = (w * 2 + it) * 64 + lane;
        int row = lc >> 2;
        int kc = (lc & 3) ^ ((row >> 1) & 3);
        gld16(&Bs[lc * 8], &W[(size_t)(n0 + row) * K + k0 + kc * 8]);
      }
    } else {
      int lc = w * 64 + lane;
      int row = lc >> 2;
      int kc = (lc & 3) ^ ((row >> 1) & 3);
      gld16(&Bs[lc * 8], &W[(size_t)(n0 + row) * K + k0 + kc * 8]);
    }
    __syncthreads();
    bfrag af[MI], bfv[4];
#pragma unroll
    for (int i = 0; i < MI; i++) {
      int r = wrow + i * 16 + l16;
      af[i] = *(const bfrag*)&As[r * 32 + (quad ^ ((r >> 1) & 3)) * 8];
    }
#pragma unroll
    for (int j = 0; j < 4; j++) {
      int r = wcol + j * 16 + l16;
      bfv[j] = *(const bfrag*)&Bs[r * 32 + (quad ^ ((r >> 1) & 3)) * 8];
    }
#pragma unroll
    for (int i = 0; i < MI; i++)
#pragma unroll
      for (int j = 0; j < 4; j++)
        acc[i][j] = __builtin_amdgcn_mfma_f32_16x16x32_bf16(af[i], bfv[j], acc[i][j], 0, 0, 0);
    __syncthreads();
  }
#pragma unroll
  for (int i = 0; i < MI; i++) {
    int mrow = m0 + wrow + i * 16 + quad * 4;
#pragma unroll
    for (int j = 0; j < 4; j++) {
      int ncol = n0 + wcol + j * 16 + l16;
#pragma unroll
      for (int r = 0; r < 4; r++) {
        float v = acc[i][j][r];
        size_t idx = (size_t)(mrow + r) * N + ncol;
        if (OBF) {
          Cb[idx] = __float2bfloat16(v);
        } else {
          if (res) v += res[idx];
          C[idx] = v;
        }
      }
    }
  }
}

// ---------- fused ff_up + SwiGLU ----------
__global__ __launch_bounds__(256) void k_ffup(const bf16* __restrict__ A,
                                              const bf16* __restrict__ Wup,
                                              bf16* __restrict__ Out) {
  __shared__ __align__(16) bf16 As[128 * 32];
  __shared__ __align__(16) bf16 Ba[64 * 32];
  __shared__ __align__(16) bf16 Bg[64 * 32];
  const int t = threadIdx.x, w = t >> 6, lane = t & 63;
  const int m0 = blockIdx.y * 128, n0 = blockIdx.x * 64;
  const int quad = lane >> 4, l16 = lane & 15;

  ffrag aa[2][4], ag[2][4];
#pragma unroll
  for (int i = 0; i < 2; i++)
#pragma unroll
    for (int j = 0; j < 4; j++) {
      aa[i][j] = (ffrag){0.f, 0.f, 0.f, 0.f};
      ag[i][j] = (ffrag){0.f, 0.f, 0.f, 0.f};
    }

  for (int k0 = 0; k0 < DM; k0 += 32) {
#pragma unroll
    for (int it = 0; it < 2; it++) {
      int lc = (w * 2 + it) * 64 + lane;
      int row = lc >> 2;
      int kc = (lc & 3) ^ ((row >> 1) & 3);
      gld16(&As[lc * 8], &A[(size_t)(m0 + row) * DM + k0 + kc * 8]);
    }
    {
      int lc = w * 64 + lane;
      int row = lc >> 2;
      int kc = (lc & 3) ^ ((row >> 1) & 3);
      gld16(&Ba[lc * 8], &Wup[(size_t)(n0 + row) * DM + k0 + kc * 8]);
      gld16(&Bg[lc * 8], &Wup[(size_t)(DFF + n0 + row) * DM + k0 + kc * 8]);
    }
    __syncthreads();
    bfrag af[2], ba[4], bg[4];
#pragma unroll
    for (int i = 0; i < 2; i++) {
      int r = w * 32 + i * 16 + l16;
      af[i] = *(const bfrag*)&As[r * 32 + (quad ^ ((r >> 1) & 3)) * 8];
    }
#pragma unroll
    for (int j = 0; j < 4; j++) {
      int r = j * 16 + l16;
      int sw = (quad ^ ((r >> 1) & 3)) * 8;
      ba[j] = *(const bfrag*)&Ba[r * 32 + sw];
      bg[j] = *(const bfrag*)&Bg[r * 32 + sw];
    }
#pragma unroll
    for (int i = 0; i < 2; i++)
#pragma unroll
      for (int j = 0; j < 4; j++) {
        aa[i][j] = __builtin_amdgcn_mfma_f32_16x16x32_bf16(af[i], ba[j], aa[i][j], 0, 0, 0);
        ag[i][j] = __builtin_amdgcn_mfma_f32_16x16x32_bf16(af[i], bg[j], ag[i][j], 0, 0, 0);
      }
    __syncthreads();
  }
#pragma unroll
  for (int i = 0; i < 2; i++) {
    int mrow = m0 + w * 32 + i * 16 + quad * 4;
#pragma unroll
    for (int j = 0; j < 4; j++) {
      int ncol = n0 + j * 16 + l16;
#pragma unroll
      for (int r = 0; r < 4; r++) {
        float a = aa[i][j][r], g = ag[i][j][r];
        float v = a * g / (1.f + __expf(-g));
        Out[(size_t)(mrow + r) * DFF + ncol] = __float2bfloat16(v);
      }
    }
  }
}

// ---------- cos-scale + RoPE for Q and K in one pass; one wave per (b,h,l) ----------
__device__ __forceinline__ float rope_apply(float x, const float* __restrict__ pos3, float s,
                                            int h, int lane) {
  float ss = x * x;
#pragma unroll
  for (int m = 32; m > 0; m >>= 1) ss += __shfl_xor(ss, m, 64);
  x *= s * rsqrtf(ss + 1e-6f);
  int j = lane < 24 ? lane : (lane < 48 ? lane - 24 : 0);
  int partner = lane < 24 ? lane + 24 : (lane < 48 ? lane - 24 : lane);
  float other = __shfl(x, partner, 64);
  if (lane < 48) {
    int c = j >> 3, f = j & 7;
    // ROPE_FREQS[h][f] = pi * 10^((f*12+h)/96)
    float fr = __expf(1.14472988584940017f +
                      (float)(f * 12 + h) * (2.30258509299404568f / 96.0f));
    float th = pos3[c] * fr;
    float st, ct;
    sincosf(th, &st, &ct);
    return (lane < 24) ? (x * ct - other * st) : (x * ct + other * st);
  }
  return x;
}

__global__ __launch_bounds__(256) void k_ropeqk(const bf16* __restrict__ inQ, int strQ, int offQ,
                                                const bf16* __restrict__ inK, int strK, int offK,
                                                const float* __restrict__ posQ,
                                                const float* __restrict__ posK,
                                                const float* __restrict__ scale,
                                                bf16* __restrict__ outQ, bf16* __restrict__ outK) {
  int item = blockIdx.x * 4 + (threadIdx.x >> 6); // (b*NH + h)*L + l
  int lane = threadIdx.x & 63;
  int l = item % L;
  int bh = item / L;
  int h = bh % NH;
  int b = bh / NH;
  float s = sqrtf(scale[h]);
  size_t tokrow = (size_t)(b * L + l);
  float xq = __bfloat162float(inQ[tokrow * strQ + offQ + h * DH + lane]);
  float oq = rope_apply(xq, &posQ[tokrow * 3], s, h, lane);
  outQ[(size_t)item * DH + lane] = __float2bfloat16(oq);
  float xk = __bfloat162float(inK[tokrow * strK + offK + h * DH + lane]);
  float ok = rope_apply(xk, &posK[tokrow * 3], s, h, lane);
  outK[(size_t)item * DH + lane] = __float2bfloat16(ok);
}

// ---------- V transpose: (b,l,h,d)-strided slice -> Vt (bh, DH, L), coalesced b128 out ----------
__global__ __launch_bounds__(256) void k_vtrans(const bf16* __restrict__ in, int stride, int off,
                                                bf16* __restrict__ Vt) {
  __shared__ __align__(16) bf16 St[64 * 64];
  int lt = blockIdx.x & 31, bh = blockIdx.x >> 5;
  int h = bh % NH, b = bh / NH;
  int t = threadIdx.x;
#pragma unroll
  for (int pass = 0; pass < 2; pass++) {
    int cid = t + pass * 256;
    int r = cid >> 3, c = cid & 7; // token r, d-chunk c
    *(float4*)&St[ASW(r, c)] =
        *(const float4*)&in[(size_t)(b * L + lt * 64 + r) * stride + off + h * DH + c * 8];
  }
  __syncthreads();
  const short* Ss = (const short*)St;
#pragma unroll
  for (int pass = 0; pass < 2; pass++) {
    int cid = t + pass * 256;
    int d = cid >> 3, oc = cid & 7; // out row d, token-chunk oc
    bfrag tmp;
#pragma unroll
    for (int i = 0; i < 8; i++) {
      int tok = oc * 8 + i;
      tmp[i] = Ss[(tok << 6) + ((((d >> 3) ^ (tok & 7))) << 3) + (d & 7)];
    }
    *(bfrag*)&Vt[((size_t)bh * DH + d) * L + lt * 64 + oc * 8] = tmp;
  }
}

// ---------- MFMA flash attention, 32x32x16, fixed-bound softmax ----------
// Q,K: (BH, L, DH) bf16; Vt: (BH, DH, L) bf16; O: (B, L, NH, DH) bf16
// Wave (qsub,ksub) computes S^T = K.Q^T for its 32x32 subtile (q in lane index ->
// scalar in-lane l accumulation), writes P[q][key], then PV over its OWN 32 keys
// (in-wave RAW, no extra barrier). Cross-ksub O/l merge once at the end via LDS.
__global__ __launch_bounds__(256) void k_attn_mfma(const bf16* __restrict__ Q,
                                                   const bf16* __restrict__ K,
                                                   const bf16* __restrict__ Vt,
                                                   const float* __restrict__ scale,
                                                   bf16* __restrict__ O) {
  __shared__ __align__(16) char smem[24576 + 512];
  bf16* Ks = (bf16*)smem;              // 8KB [key][d]
  bf16* Vs = (bf16*)(smem + 8192);     // 8KB [d][key]
  bf16* Ps = (bf16*)(smem + 16384);    // 8KB [q][key]
  float* Oex = (float*)smem;           // 16KB overlay (after final barrier)
  float* Lred = (float*)(smem + 24576); // 2*64
  int qt = blockIdx.x & 31, bh = blockIdx.x >> 5;
  int h = bh % NH, b = bh / NH;
  float smax = scale[h];
  int t = threadIdx.x, w = t >> 6, lane = t & 63;
  int hh = lane >> 5, l32 = lane & 31;
  int qsub = w >> 1, ksub = w & 1;
  int sr = t >> 3, sc = t & 7;

  const bf16* kbase = K + (size_t)(bh * L) * DH;
  const bf16* vbase = Vt + (size_t)bh * DH * L;

  // Q B-frags in registers (q = qsub*32 + l32, d-chunks)
  const bf16* qrow = Q + ((size_t)(bh * L) + qt * 64 + qsub * 32 + l32) * DH;
  bfrag qf[4];
#pragma unroll
  for (int c = 0; c < 4; c++) qf[c] = *(const bfrag*)&qrow[c * 16 + hh * 8];

  facc16 o0, o1;
#pragma unroll
  for (int i = 0; i < 16; i++) { o0[i] = 0.f; o1[i] = 0.f; }
  float l_run = 0.f;
  int qg = qsub * 32 + l32;

  for (int kt = 0; kt < 32; kt++) {
    int k0 = kt * 64;
    __syncthreads();
#pragma unroll
    for (int half = 0; half < 2; half++) {
      int r = sr + half * 32;
      *(float4*)&Ks[ASW(r, sc)] = *(const float4*)&kbase[(size_t)(k0 + r) * DH + sc * 8];
      *(float4*)&Vs[ASW(r, sc)] = *(const float4*)&vbase[(size_t)r * L + k0 + sc * 8];
    }
    __syncthreads();
    // ---- S^T = K·Q^T (m=key 32 of ksub, n=q 32 of qsub, k=d 64) ----
    facc16 s;
#pragma unroll
    for (int i = 0; i < 16; i++) s[i] = 0.f;
#pragma unroll
    for (int c = 0; c < 4; c++) {
      bfrag kf = *(const bfrag*)&Ks[ASW(ksub * 32 + l32, c * 2 + hh)];
      s = __builtin_amdgcn_mfma_f32_32x32x16_bf16(kf, qf[c], s, 0, 0, 0);
    }
    // ---- p = exp(s - smax); in-lane l; write P[q][key] ----
#pragma unroll
    for (int reg = 0; reg < 16; reg++) {
      float p = __expf(s[reg] - smax);
      l_run += p;
      int keyg = ksub * 32 + (reg & 3) + 8 * (reg >> 2) + 4 * hh;
      Ps[(qg << 6) + ((((keyg >> 3) ^ (qg & 7))) << 3) + (keyg & 7)] = __float2bfloat16(p);
    }
    // ---- O partial += P(own keys) · V  (in-wave RAW on Ps) ----
    bfrag pf0 = *(const bfrag*)&Ps[ASW(qg, ksub * 4 + hh)];
    bfrag pf1 = *(const bfrag*)&Ps[ASW(qg, ksub * 4 + 2 + hh)];
    {
      bfrag vf;
      vf = *(const bfrag*)&Vs[ASW(l32, ksub * 4 + hh)];
      o0 = __builtin_amdgcn_mfma_f32_32x32x16_bf16(pf0, vf, o0, 0, 0, 0);
      vf = *(const bfrag*)&Vs[ASW(l32, ksub * 4 + 2 + hh)];
      o0 = __builtin_amdgcn_mfma_f32_32x32x16_bf16(pf1, vf, o0, 0, 0, 0);
      vf = *(const bfrag*)&Vs[ASW(32 + l32, ksub * 4 + hh)];
      o1 = __builtin_amdgcn_mfma_f32_32x32x16_bf16(pf0, vf, o1, 0, 0, 0);
      vf = *(const bfrag*)&Vs[ASW(32 + l32, ksub * 4 + 2 + hh)];
      o1 = __builtin_amdgcn_mfma_f32_32x32x16_bf16(pf1, vf, o1, 0, 0, 0);
    }
  }
  // ---- merge halves of l (keys split across lane halves) ----
  l_run += __shfl_xor(l_run, 32, 64);
  __syncthreads(); // all PV reads done; Ks/Vs reusable as Oex
  // give away the d-half this wave does NOT own
  {
    int gd = (ksub ^ 1) * 32 + l32;
#pragma unroll
    for (int reg = 0; reg < 16; reg++) {
      int row = (reg & 3) + 8 * (reg >> 2) + 4 * hh;
      float gv = ksub ? o0[reg] : o1[reg];
      Oex[(size_t)(qsub * 32 + row) * 64 + gd] = gv;
    }
  }
  if (lane < 32) Lred[ksub * 64 + qsub * 32 + lane] = l_run;
  __syncthreads();
  // combine + normalize + store
  {
    int d = ksub * 32 + l32;
#pragma unroll
    for (int reg = 0; reg < 16; reg++) {
      int row = (reg & 3) + 8 * (reg >> 2) + 4 * hh;
      int qg2 = qsub * 32 + row;
      float ltot = Lred[qg2] + Lred[64 + qg2];
      float keep = ksub ? o1[reg] : o0[reg];
      float v = (keep + Oex[(size_t)qg2 * 64 + d]) / ltot;
      O[(((size_t)(b * L) + qt * 64 + qg2) * NH + h) * DH + d] = __float2bfloat16(v);
    }
  }
}

extern "C" void kernel_launch(void* const* d_in, const int* in_sizes, int n_in,
                              void* d_out, int out_size, void* d_ws, size_t ws_size,
                              hipStream_t stream) {
  const float* x = (const float*)d_in[0];
  const float* pos = (const float*)d_in[1];
  const float* x_cross = (const float*)d_in[2];
  const float* pos_cross = (const float*)d_in[3];
  const float* sa_norm_scale = (const float*)d_in[4];
  const float* sa_wqkv = (const float*)d_in[5];
  const float* sa_scale = (const float*)d_in[6];
  const float* sa_wout = (const float*)d_in[7];
  const float* ca_norm_scale = (const float*)d_in[8];
  const float* ca_norm_cross_scale = (const float*)d_in[9];
  const float* ca_wq = (const float*)d_in[10];
  const float* ca_wkv = (const float*)d_in[11];
  const float* ca_scale = (const float*)d_in[12];
  const float* ca_wout = (const float*)d_in[13];
  const float* ff_norm_scale = (const float*)d_in[14];
  const float* ff_wup = (const float*)d_in[15];
  const float* ff_wdown = (const float*)d_in[16];
  float* out = (float*)d_out;

  float* ws = (float*)d_ws;
  const size_t S = (size_t)M_TOK * DM; // 3,145,728
  float* xbuf = ws; // S f32: running residual
  bf16* b16 = (bf16*)(ws + S);
  bf16* qkvb = b16;        // 3S: qkv (self) / caq + cakv (cross) / ffact (FF)
  bf16* qb = b16 + 3 * S;  // (BH, L, DH)
  bf16* kb = b16 + 4 * S;  // (BH, L, DH)
  bf16* vtb = b16 + 5 * S; // (BH, DH, L)
  bf16* hb = b16 + 6 * S;
  bf16* hcb = b16 + 7 * S;
  bf16* obb = b16 + 8 * S; // attn out (B,L,NH,DH)
  bf16* wqkvb = b16 + 9 * S; // weight arena: 17*DM*DM contiguous, castall order
  bf16* woutb = wqkvb + (size_t)3 * DM * DM;
  bf16* wqb = woutb + (size_t)DM * DM;
  bf16* wkvb = wqb + (size_t)DM * DM;
  bf16* wout2b = wkvb + (size_t)2 * DM * DM;
  bf16* wupb = wout2b + (size_t)DM * DM;
  bf16* wdownb = wupb + (size_t)2 * DFF * DM;
  bf16* ffb = qkvb;

  const int ropeGrid = B * NH * L / 4;
  const int attnGrid = B * NH * (L / 64); // 768
  const int vtGrid = B * NH * (L / 64);   // 768
  const size_t DM2 = (size_t)DM * DM;
  const int castGrid = (int)((17 * DM2 / 4 + 255) / 256);

  k_castall<<<castGrid, 256, 0, stream>>>(sa_wqkv, sa_wout, ca_wq, ca_wkv, ca_wout, ff_wup,
                                          ff_wdown, wqkvb);

  // ---- prologue: cross norm ----
  k_rmsnorm<<<M_TOK, 256, 0, stream>>>(x_cross, ca_norm_cross_scale, hcb);

  // ---- self attention ----
  k_rmsnorm<<<M_TOK, 256, 0, stream>>>(x, sa_norm_scale, hb);
  k_gemm<128, 1><<<dim3(3 * DM / 128, M_TOK / 128), 256, 0, stream>>>(
      hb, wqkvb, nullptr, qkvb, nullptr, M_TOK, 3 * DM, DM);
  k_ropeqk<<<ropeGrid, 256, 0, stream>>>(qkvb, 3 * DM, 0, qkvb, 3 * DM, DM, pos, pos, sa_scale,
                                         qb, kb);
  k_vtrans<<<vtGrid, 256, 0, stream>>>(qkvb, 3 * DM, 2 * DM, vtb);
  k_attn_mfma<<<attnGrid, 256, 0, stream>>>(qb, kb, vtb, sa_scale, obb);
  k_gemm<64, 0><<<dim3(DM / 64, M_TOK / 128), 256, 0, stream>>>(
      obb, woutb, xbuf, nullptr, x, M_TOK, DM, DM); // xbuf = attn@wout + x

  // ---- cross attention ----
  k_rmsnorm<<<M_TOK, 256, 0, stream>>>(xbuf, ca_norm_scale, hb);
  k_gemm<64, 1><<<dim3(DM / 64, M_TOK / 128), 256, 0, stream>>>(
      hb, wqb, nullptr, qkvb, nullptr, M_TOK, DM, DM);
  k_gemm<128, 1><<<dim3(2 * DM / 128, M_TOK / 128), 256, 0, stream>>>(
      hcb, wkvb, nullptr, qkvb + S, nullptr, M_TOK, 2 * DM, DM);
  k_ropeqk<<<ropeGrid, 256, 0, stream>>>(qkvb, DM, 0, qkvb + S, 2 * DM, 0, pos, pos_cross,
                                         ca_scale, qb, kb);
  k_vtrans<<<vtGrid, 256, 0, stream>>>(qkvb + S, 2 * DM, DM, vtb);
  k_attn_mfma<<<attnGrid, 256, 0, stream>>>(qb, kb, vtb, ca_scale, obb);
  k_gemm<64, 0><<<dim3(DM / 64, M_TOK / 128), 256, 0, stream>>>(
      obb, wout2b, xbuf, nullptr, xbuf, M_TOK, DM, DM);

  // ---- feed-forward (fused up+SwiGLU, then down) ----
  k_rmsnorm<<<M_TOK, 256, 0, stream>>>(xbuf, ff_norm_scale, hb);
  k_ffup<<<dim3(DFF / 64, M_TOK / 128), 256, 0, stream>>>(hb, wupb, ffb);
  k_gemm<64, 0><<<dim3(DM / 64, M_TOK / 128), 256, 0, stream>>>(
      ffb, wdownb, out, nullptr, xbuf, M_TOK, DM, DFF);
}

// Round 9
// 485.547 us; speedup vs baseline: 23.1243x; 1.0091x over previous
//
#include <hip/hip_runtime.h>
#include <hip/hip_bf16.h>
#include <math.h>

typedef __hip_bfloat16 bf16;

#define B 2
#define L 2048
#define DM 768
#define NH 12
#define DH 64
#define DFF 2304
#define M_TOK (B * L) // 4096

typedef __attribute__((ext_vector_type(8))) short bfrag;
typedef __attribute__((ext_vector_type(4))) float ffrag;
typedef __attribute__((ext_vector_type(16))) float facc16;

__device__ __forceinline__ float waveSum(float v) {
#pragma unroll
  for (int o = 32; o > 0; o >>= 1) v += __shfl_down(v, o, 64);
  return v;
}

__device__ __forceinline__ void gld16(void* l, const void* g) {
  __builtin_amdgcn_global_load_lds((const __attribute__((address_space(1))) unsigned*)g,
                                   (__attribute__((address_space(3))) unsigned*)l, 16, 0, 0);
}

// element-index swizzle for 64-col bf16 LDS tiles (16B chunk XOR row&7)
#define ASW(row, chunk) (((row) << 6) + ((((chunk) ^ ((row)&7))) << 3))

// ---------- fused weight cast fp32 -> bf16 (7 segments, contiguous dst arena) ----------
__global__ void k_castall(const float* __restrict__ s0, const float* __restrict__ s1,
                          const float* __restrict__ s2, const float* __restrict__ s3,
                          const float* __restrict__ s4, const float* __restrict__ s5,
                          const float* __restrict__ s6, bf16* __restrict__ dst) {
  const size_t DM2 = (size_t)DM * DM;
  size_t u = ((size_t)blockIdx.x * 256 + threadIdx.x) * 4;
  if (u >= 17 * DM2) return;
  const float* src;
  size_t loc;
  if (u < 3 * DM2) { src = s0; loc = u; }
  else if (u < 4 * DM2) { src = s1; loc = u - 3 * DM2; }
  else if (u < 5 * DM2) { src = s2; loc = u - 4 * DM2; }
  else if (u < 7 * DM2) { src = s3; loc = u - 5 * DM2; }
  else if (u < 8 * DM2) { src = s4; loc = u - 7 * DM2; }
  else if (u < 14 * DM2) { src = s5; loc = u - 8 * DM2; }
  else { src = s6; loc = u - 14 * DM2; }
  float4 v = *(const float4*)&src[loc];
  bf16* d = dst + u;
  d[0] = __float2bfloat16(v.x);
  d[1] = __float2bfloat16(v.y);
  d[2] = __float2bfloat16(v.z);
  d[3] = __float2bfloat16(v.w);
}

// ---------- RMSNorm: one block (256 thr) per row of 768; bf16 out ----------
__global__ __launch_bounds__(256) void k_rmsnorm(const float* __restrict__ in,
                                                 const float* __restrict__ scale,
                                                 bf16* __restrict__ out) {
  int row = blockIdx.x;
  int t = threadIdx.x;
  const float* r = in + (size_t)row * DM;
  float x0 = r[t], x1 = r[t + 256], x2 = r[t + 512];
  float ss = x0 * x0 + x1 * x1 + x2 * x2;
  ss = waveSum(ss);
  __shared__ float red[4];
  int w = t >> 6, ln = t & 63;
  if (ln == 0) red[w] = ss;
  __syncthreads();
  float tot = red[0] + red[1] + red[2] + red[3];
  float g = rsqrtf(tot / (float)DM + 1e-6f);
  bf16* o = out + (size_t)row * DM;
  o[t] = __float2bfloat16(x0 * g * scale[t]);
  o[t + 256] = __float2bfloat16(x1 * g * scale[t + 256]);
  o[t + 512] = __float2bfloat16(x2 * g * scale[t + 512]);
}

// ---------- MFMA GEMM, double-buffered K-loop ----------
// barrier -> issue async loads(k+1) -> compute(k): the vmcnt drain at the NEXT
// barrier lands after a full compute phase (latency hidden at 1 block/CU).
template <int NT, int OBF>
__global__ __launch_bounds__(256) void k_gemm(const bf16* __restrict__ A,
                                              const bf16* __restrict__ W,
                                              float* __restrict__ C,
                                              bf16* __restrict__ Cb,
                                              const float* __restrict__ res,
                                              int M, int N, int K) {
  __shared__ __align__(16) bf16 As[2 * 128 * 32];
  __shared__ __align__(16) bf16 Bs[2 * NT * 32];
  const int t = threadIdx.x;
  const int w = t >> 6, lane = t & 63;
  const int m0 = blockIdx.y * 128, n0 = blockIdx.x * NT;
  const int quad = lane >> 4, l16 = lane & 15;
  constexpr int MI = (NT == 128) ? 4 : 2;
  const int wrow = (NT == 128) ? (w >> 1) * 64 : w * 32;
  const int wcol = (NT == 128) ? (w & 1) * 64 : 0;

  ffrag acc[MI][4];
#pragma unroll
  for (int i = 0; i < MI; i++)
#pragma unroll
    for (int j = 0; j < 4; j++) acc[i][j] = (ffrag){0.f, 0.f, 0.f, 0.f};

  auto stage = [&](int k0, int sel) {
#pragma unroll
    for (int it = 0; it < 2; it++) {
      int lc = (w * 2 + it) * 64 + lane;
      int row = lc >> 2;
      int kc = (lc & 3) ^ ((row >> 1) & 3);
      gld16(&As[sel * 4096 + lc * 8], &A[(size_t)(m0 + row) * K + k0 + kc * 8]);
    }
    if (NT == 128) {
#pragma unroll
      for (int it = 0; it < 2; it++) {
        int lc = (w * 2 + it) * 64 + lane;
        int row = lc >> 2;
        int kc = (lc & 3) ^ ((row >> 1) & 3);
        gld16(&Bs[sel * 4096 + lc * 8], &W[(size_t)(n0 + row) * K + k0 + kc * 8]);
      }
    } else {
      int lc = w * 64 + lane;
      int row = lc >> 2;
      int kc = (lc & 3) ^ ((row >> 1) & 3);
      gld16(&Bs[sel * 2048 + lc * 8], &W[(size_t)(n0 + row) * K + k0 + kc * 8]);
    }
  };

  const int NK = K >> 5;
  stage(0, 0);
  for (int kt = 0; kt < NK; kt++) {
    int cur = kt & 1;
    __syncthreads(); // tile kt ready; buffer cur^1 free
    if (kt + 1 < NK) stage((kt + 1) * 32, cur ^ 1);
    const bf16* Ab = As + cur * 4096;
    const bf16* Bb = Bs + cur * (NT == 128 ? 4096 : 2048);
    bfrag af[MI], bfv[4];
#pragma unroll
    for (int i = 0; i < MI; i++) {
      int r = wrow + i * 16 + l16;
      af[i] = *(const bfrag*)&Ab[r * 32 + (quad ^ ((r >> 1) & 3)) * 8];
    }
#pragma unroll
    for (int j = 0; j < 4; j++) {
      int r = wcol + j * 16 + l16;
      bfv[j] = *(const bfrag*)&Bb[r * 32 + (quad ^ ((r >> 1) & 3)) * 8];
    }
#pragma unroll
    for (int i = 0; i < MI; i++)
#pragma unroll
      for (int j = 0; j < 4; j++)
        acc[i][j] = __builtin_amdgcn_mfma_f32_16x16x32_bf16(af[i], bfv[j], acc[i][j], 0, 0, 0);
  }
#pragma unroll
  for (int i = 0; i < MI; i++) {
    int mrow = m0 + wrow + i * 16 + quad * 4;
#pragma unroll
    for (int j = 0; j < 4; j++) {
      int ncol = n0 + wcol + j * 16 + l16;
#pragma unroll
      for (int r = 0; r < 4; r++) {
        float v = acc[i][j][r];
        size_t idx = (size_t)(mrow + r) * N + ncol;
        if (OBF) {
          Cb[idx] = __float2bfloat16(v);
        } else {
          if (res) v += res[idx];
          C[idx] = v;
        }
      }
    }
  }
}

// ---------- fused ff_up + SwiGLU, double-buffered ----------
__global__ __launch_bounds__(256) void k_ffup(const bf16* __restrict__ A,
                                              const bf16* __restrict__ Wup,
                                              bf16* __restrict__ Out) {
  __shared__ __align__(16) bf16 As[2 * 128 * 32];
  __shared__ __align__(16) bf16 Ba[2 * 64 * 32];
  __shared__ __align__(16) bf16 Bg[2 * 64 * 32];
  const int t = threadIdx.x, w = t >> 6, lane = t & 63;
  const int m0 = blockIdx.y * 128, n0 = blockIdx.x * 64;
  const int quad = lane >> 4, l16 = lane & 15;

  ffrag aa[2][4], ag[2][4];
#pragma unroll
  for (int i = 0; i < 2; i++)
#pragma unroll
    for (int j = 0; j < 4; j++) {
      aa[i][j] = (ffrag){0.f, 0.f, 0.f, 0.f};
      ag[i][j] = (ffrag){0.f, 0.f, 0.f, 0.f};
    }

  auto stage = [&](int k0, int sel) {
#pragma unroll
    for (int it = 0; it < 2; it++) {
      int lc = (w * 2 + it) * 64 + lane;
      int row = lc >> 2;
      int kc = (lc & 3) ^ ((row >> 1) & 3);
      gld16(&As[sel * 4096 + lc * 8], &A[(size_t)(m0 + row) * DM + k0 + kc * 8]);
    }
    {
      int lc = w * 64 + lane;
      int row = lc >> 2;
      int kc = (lc & 3) ^ ((row >> 1) & 3);
      gld16(&Ba[sel * 2048 + lc * 8], &Wup[(size_t)(n0 + row) * DM + k0 + kc * 8]);
      gld16(&Bg[sel * 2048 + lc * 8], &Wup[(size_t)(DFF + n0 + row) * DM + k0 + kc * 8]);
    }
  };

  const int NK = DM / 32;
  stage(0, 0);
  for (int kt = 0; kt < NK; kt++) {
    int cur = kt & 1;
    __syncthreads();
    if (kt + 1 < NK) stage((kt + 1) * 32, cur ^ 1);
    const bf16* Ab = As + cur * 4096;
    const bf16* Bab = Ba + cur * 2048;
    const bf16* Bgb = Bg + cur * 2048;
    bfrag af[2], ba[4], bg[4];
#pragma unroll
    for (int i = 0; i < 2; i++) {
      int r = w * 32 + i * 16 + l16;
      af[i] = *(const bfrag*)&Ab[r * 32 + (quad ^ ((r >> 1) & 3)) * 8];
    }
#pragma unroll
    for (int j = 0; j < 4; j++) {
      int r = j * 16 + l16;
      int sw = (quad ^ ((r >> 1) & 3)) * 8;
      ba[j] = *(const bfrag*)&Bab[r * 32 + sw];
      bg[j] = *(const bfrag*)&Bgb[r * 32 + sw];
    }
#pragma unroll
    for (int i = 0; i < 2; i++)
#pragma unroll
      for (int j = 0; j < 4; j++) {
        aa[i][j] = __builtin_amdgcn_mfma_f32_16x16x32_bf16(af[i], ba[j], aa[i][j], 0, 0, 0);
        ag[i][j] = __builtin_amdgcn_mfma_f32_16x16x32_bf16(af[i], bg[j], ag[i][j], 0, 0, 0);
      }
  }
#pragma unroll
  for (int i = 0; i < 2; i++) {
    int mrow = m0 + w * 32 + i * 16 + quad * 4;
#pragma unroll
    for (int j = 0; j < 4; j++) {
      int ncol = n0 + j * 16 + l16;
#pragma unroll
      for (int r = 0; r < 4; r++) {
        float a = aa[i][j][r], g = ag[i][j][r];
        float v = a * g / (1.f + __expf(-g));
        Out[(size_t)(mrow + r) * DFF + ncol] = __float2bfloat16(v);
      }
    }
  }
}

// ---------- cos-scale + RoPE for Q and K in one pass; one wave per (b,h,l) ----------
__device__ __forceinline__ float rope_apply(float x, const float* __restrict__ pos3, float s,
                                            int h, int lane) {
  float ss = x * x;
#pragma unroll
  for (int m = 32; m > 0; m >>= 1) ss += __shfl_xor(ss, m, 64);
  x *= s * rsqrtf(ss + 1e-6f);
  int j = lane < 24 ? lane : (lane < 48 ? lane - 24 : 0);
  int partner = lane < 24 ? lane + 24 : (lane < 48 ? lane - 24 : lane);
  float other = __shfl(x, partner, 64);
  if (lane < 48) {
    int c = j >> 3, f = j & 7;
    // ROPE_FREQS[h][f] = pi * 10^((f*12+h)/96)
    float fr = __expf(1.14472988584940017f +
                      (float)(f * 12 + h) * (2.30258509299404568f / 96.0f));
    float th = pos3[c] * fr;
    float st, ct;
    sincosf(th, &st, &ct);
    return (lane < 24) ? (x * ct - other * st) : (x * ct + other * st);
  }
  return x;
}

__global__ __launch_bounds__(256) void k_ropeqk(const bf16* __restrict__ inQ, int strQ, int offQ,
                                                const bf16* __restrict__ inK, int strK, int offK,
                                                const float* __restrict__ posQ,
                                                const float* __restrict__ posK,
                                                const float* __restrict__ scale,
                                                bf16* __restrict__ outQ, bf16* __restrict__ outK) {
  int item = blockIdx.x * 4 + (threadIdx.x >> 6); // (b*NH + h)*L + l
  int lane = threadIdx.x & 63;
  int l = item % L;
  int bh = item / L;
  int h = bh % NH;
  int b = bh / NH;
  float s = sqrtf(scale[h]);
  size_t tokrow = (size_t)(b * L + l);
  float xq = __bfloat162float(inQ[tokrow * strQ + offQ + h * DH + lane]);
  float oq = rope_apply(xq, &posQ[tokrow * 3], s, h, lane);
  outQ[(size_t)item * DH + lane] = __float2bfloat16(oq);
  float xk = __bfloat162float(inK[tokrow * strK + offK + h * DH + lane]);
  float ok = rope_apply(xk, &posK[tokrow * 3], s, h, lane);
  outK[(size_t)item * DH + lane] = __float2bfloat16(ok);
}

// ---------- V transpose: (b,l,h,d)-strided slice -> Vt (bh, DH, L) ----------
__global__ __launch_bounds__(256) void k_vtrans(const bf16* __restrict__ in, int stride, int off,
                                                bf16* __restrict__ Vt) {
  __shared__ __align__(16) bf16 St[64 * 64];
  int lt = blockIdx.x & 31, bh = blockIdx.x >> 5;
  int h = bh % NH, b = bh / NH;
  int t = threadIdx.x;
#pragma unroll
  for (int pass = 0; pass < 2; pass++) {
    int cid = t + pass * 256;
    int r = cid >> 3, c = cid & 7; // token r, d-chunk c
    *(float4*)&St[ASW(r, c)] =
        *(const float4*)&in[(size_t)(b * L + lt * 64 + r) * stride + off + h * DH + c * 8];
  }
  __syncthreads();
  const short* Ss = (const short*)St;
#pragma unroll
  for (int pass = 0; pass < 2; pass++) {
    int cid = t + pass * 256;
    int d = cid >> 3, oc = cid & 7; // out row d, token-chunk oc
    bfrag tmp;
#pragma unroll
    for (int i = 0; i < 8; i++) {
      int tok = oc * 8 + i;
      tmp[i] = Ss[(tok << 6) + ((((d >> 3) ^ (tok & 7))) << 3) + (d & 7)];
    }
    *(bfrag*)&Vt[((size_t)bh * DH + d) * L + lt * 64 + oc * 8] = tmp;
  }
}

// ---------- MFMA flash attention, 32x32x16, fixed-bound softmax, dbuf KV ----------
// Staging via global_load_lds: LDS dst is linear (wave-uniform base + lane*16);
// the ASW swizzle is realized by permuting the GLOBAL source chunk per lane.
__global__ __launch_bounds__(256) void k_attn_mfma(const bf16* __restrict__ Q,
                                                   const bf16* __restrict__ K,
                                                   const bf16* __restrict__ Vt,
                                                   const float* __restrict__ scale,
                                                   bf16* __restrict__ O) {
  __shared__ __align__(16) char smem[40960 + 512];
  bf16* Ks = (bf16*)smem;               // 2 x 8KB [key][d]
  bf16* Vs = (bf16*)(smem + 16384);     // 2 x 8KB [d][key]
  bf16* Ps = (bf16*)(smem + 32768);     // 8KB [q][key]
  float* Oex = (float*)smem;            // 16KB overlay (after final barrier)
  float* Lred = (float*)(smem + 40960); // 2*64
  int qt = blockIdx.x & 31, bh = blockIdx.x >> 5;
  int h = bh % NH, b = bh / NH;
  float smax = scale[h];
  int t = threadIdx.x, w = t >> 6, lane = t & 63;
  int hh = lane >> 5, l32 = lane & 31;
  int qsub = w >> 1, ksub = w & 1;

  const bf16* kbase = K + (size_t)(bh * L) * DH;
  const bf16* vbase = Vt + (size_t)bh * DH * L;

  // Q B-frags in registers (q = qsub*32 + l32, d-chunks)
  const bf16* qrow = Q + ((size_t)(bh * L) + qt * 64 + qsub * 32 + l32) * DH;
  bfrag qf[4];
#pragma unroll
  for (int c = 0; c < 4; c++) qf[c] = *(const bfrag*)&qrow[c * 16 + hh * 8];

  facc16 o0, o1;
#pragma unroll
  for (int i = 0; i < 16; i++) { o0[i] = 0.f; o1[i] = 0.f; }
  float l_run = 0.f;
  int qg = qsub * 32 + l32;

  auto stageKV = [&](int kt, int sel) {
    int k0 = kt * 64;
    bf16* Kb = Ks + sel * 4096;
    bf16* Vb = Vs + sel * 4096;
#pragma unroll
    for (int h2 = 0; h2 < 2; h2++) {
      int r = w * 8 + (lane >> 3) + h2 * 32;
      int kc = (lane & 7) ^ (r & 7);
      int ldsrow = (w * 8 + h2 * 32) * 64;
      gld16(&Kb[ldsrow + lane * 8], &kbase[(size_t)(k0 + r) * DH + kc * 8]);
      gld16(&Vb[ldsrow + lane * 8], &vbase[(size_t)r * L + k0 + kc * 8]);
    }
  };

  stageKV(0, 0);
  for (int kt = 0; kt < 32; kt++) {
    int cur = kt & 1;
    __syncthreads(); // tile kt staged; buffer cur^1 free
    if (kt < 31) stageKV(kt + 1, cur ^ 1);
    const bf16* Kb = Ks + cur * 4096;
    const bf16* Vb = Vs + cur * 4096;
    // ---- S^T = K·Q^T (m=key 32 of ksub, n=q 32 of qsub, k=d 64) ----
    facc16 s;
#pragma unroll
    for (int i = 0; i < 16; i++) s[i] = 0.f;
#pragma unroll
    for (int c = 0; c < 4; c++) {
      bfrag kf = *(const bfrag*)&Kb[ASW(ksub * 32 + l32, c * 2 + hh)];
      s = __builtin_amdgcn_mfma_f32_32x32x16_bf16(kf, qf[c], s, 0, 0, 0);
    }
    // ---- p = exp(s - smax); in-lane l; write P[q][key] ----
#pragma unroll
    for (int reg = 0; reg < 16; reg++) {
      float p = __expf(s[reg] - smax);
      l_run += p;
      int keyg = ksub * 32 + (reg & 3) + 8 * (reg >> 2) + 4 * hh;
      Ps[(qg << 6) + ((((keyg >> 3) ^ (qg & 7))) << 3) + (keyg & 7)] = __float2bfloat16(p);
    }
    // ---- O partial += P(own keys) · V  (in-wave RAW on Ps) ----
    bfrag pf0 = *(const bfrag*)&Ps[ASW(qg, ksub * 4 + hh)];
    bfrag pf1 = *(const bfrag*)&Ps[ASW(qg, ksub * 4 + 2 + hh)];
    {
      bfrag vf;
      vf = *(const bfrag*)&Vb[ASW(l32, ksub * 4 + hh)];
      o0 = __builtin_amdgcn_mfma_f32_32x32x16_bf16(pf0, vf, o0, 0, 0, 0);
      vf = *(const bfrag*)&Vb[ASW(l32, ksub * 4 + 2 + hh)];
      o0 = __builtin_amdgcn_mfma_f32_32x32x16_bf16(pf1, vf, o0, 0, 0, 0);
      vf = *(const bfrag*)&Vb[ASW(32 + l32, ksub * 4 + hh)];
      o1 = __builtin_amdgcn_mfma_f32_32x32x16_bf16(pf0, vf, o1, 0, 0, 0);
      vf = *(const bfrag*)&Vb[ASW(32 + l32, ksub * 4 + 2 + hh)];
      o1 = __builtin_amdgcn_mfma_f32_32x32x16_bf16(pf1, vf, o1, 0, 0, 0);
    }
  }
  // ---- merge halves of l (keys split across lane halves) ----
  l_run += __shfl_xor(l_run, 32, 64);
  __syncthreads(); // all PV reads done; Ks/Vs reusable as Oex
  {
    int gd = (ksub ^ 1) * 32 + l32;
#pragma unroll
    for (int reg = 0; reg < 16; reg++) {
      int row = (reg & 3) + 8 * (reg >> 2) + 4 * hh;
      float gv = ksub ? o0[reg] : o1[reg];
      Oex[(size_t)(qsub * 32 + row) * 64 + gd] = gv;
    }
  }
  if (lane < 32) Lred[ksub * 64 + qsub * 32 + lane] = l_run;
  __syncthreads();
  {
    int d = ksub * 32 + l32;
#pragma unroll
    for (int reg = 0; reg < 16; reg++) {
      int row = (reg & 3) + 8 * (reg >> 2) + 4 * hh;
      int qg2 = qsub * 32 + row;
      float ltot = Lred[qg2] + Lred[64 + qg2];
      float keep = ksub ? o1[reg] : o0[reg];
      float v = (keep + Oex[(size_t)qg2 * 64 + d]) / ltot;
      O[(((size_t)(b * L) + qt * 64 + qg2) * NH + h) * DH + d] = __float2bfloat16(v);
    }
  }
}

extern "C" void kernel_launch(void* const* d_in, const int* in_sizes, int n_in,
                              void* d_out, int out_size, void* d_ws, size_t ws_size,
                              hipStream_t stream) {
  const float* x = (const float*)d_in[0];
  const float* pos = (const float*)d_in[1];
  const float* x_cross = (const float*)d_in[2];
  const float* pos_cross = (const float*)d_in[3];
  const float* sa_norm_scale = (const float*)d_in[4];
  const float* sa_wqkv = (const float*)d_in[5];
  const float* sa_scale = (const float*)d_in[6];
  const float* sa_wout = (const float*)d_in[7];
  const float* ca_norm_scale = (const float*)d_in[8];
  const float* ca_norm_cross_scale = (const float*)d_in[9];
  const float* ca_wq = (const float*)d_in[10];
  const float* ca_wkv = (const float*)d_in[11];
  const float* ca_scale = (const float*)d_in[12];
  const float* ca_wout = (const float*)d_in[13];
  const float* ff_norm_scale = (const float*)d_in[14];
  const float* ff_wup = (const float*)d_in[15];
  const float* ff_wdown = (const float*)d_in[16];
  float* out = (float*)d_out;

  float* ws = (float*)d_ws;
  const size_t S = (size_t)M_TOK * DM; // 3,145,728
  float* xbuf = ws; // S f32: running residual
  bf16* b16 = (bf16*)(ws + S);
  bf16* qkvb = b16;        // 3S: qkv (self) / caq + cakv (cross) / ffact (FF)
  bf16* qb = b16 + 3 * S;  // (BH, L, DH)
  bf16* kb = b16 + 4 * S;  // (BH, L, DH)
  bf16* vtb = b16 + 5 * S; // (BH, DH, L)
  bf16* hb = b16 + 6 * S;
  bf16* hcb = b16 + 7 * S;
  bf16* obb = b16 + 8 * S; // attn out (B,L,NH,DH)
  bf16* wqkvb = b16 + 9 * S; // weight arena: 17*DM*DM contiguous, castall order
  bf16* woutb = wqkvb + (size_t)3 * DM * DM;
  bf16* wqb = woutb + (size_t)DM * DM;
  bf16* wkvb = wqb + (size_t)DM * DM;
  bf16* wout2b = wkvb + (size_t)2 * DM * DM;
  bf16* wupb = wout2b + (size_t)DM * DM;
  bf16* wdownb = wupb + (size_t)2 * DFF * DM;
  bf16* ffb = qkvb;

  const int ropeGrid = B * NH * L / 4;
  const int attnGrid = B * NH * (L / 64); // 768
  const int vtGrid = B * NH * (L / 64);   // 768
  const size_t DM2 = (size_t)DM * DM;
  const int castGrid = (int)((17 * DM2 / 4 + 255) / 256);

  k_castall<<<castGrid, 256, 0, stream>>>(sa_wqkv, sa_wout, ca_wq, ca_wkv, ca_wout, ff_wup,
                                          ff_wdown, wqkvb);

  // ---- prologue: cross norm ----
  k_rmsnorm<<<M_TOK, 256, 0, stream>>>(x_cross, ca_norm_cross_scale, hcb);

  // ---- self attention ----
  k_rmsnorm<<<M_TOK, 256, 0, stream>>>(x, sa_norm_scale, hb);
  k_gemm<128, 1><<<dim3(3 * DM / 128, M_TOK / 128), 256, 0, stream>>>(
      hb, wqkvb, nullptr, qkvb, nullptr, M_TOK, 3 * DM, DM);
  k_ropeqk<<<ropeGrid, 256, 0, stream>>>(qkvb, 3 * DM, 0, qkvb, 3 * DM, DM, pos, pos, sa_scale,
                                         qb, kb);
  k_vtrans<<<vtGrid, 256, 0, stream>>>(qkvb, 3 * DM, 2 * DM, vtb);
  k_attn_mfma<<<attnGrid, 256, 0, stream>>>(qb, kb, vtb, sa_scale, obb);
  k_gemm<64, 0><<<dim3(DM / 64, M_TOK / 128), 256, 0, stream>>>(
      obb, woutb, xbuf, nullptr, x, M_TOK, DM, DM); // xbuf = attn@wout + x

  // ---- cross attention ----
  k_rmsnorm<<<M_TOK, 256, 0, stream>>>(xbuf, ca_norm_scale, hb);
  k_gemm<64, 1><<<dim3(DM / 64, M_TOK / 128), 256, 0, stream>>>(
      hb, wqb, nullptr, qkvb, nullptr, M_TOK, DM, DM);
  k_gemm<128, 1><<<dim3(2 * DM / 128, M_TOK / 128), 256, 0, stream>>>(
      hcb, wkvb, nullptr, qkvb + S, nullptr, M_TOK, 2 * DM, DM);
  k_ropeqk<<<ropeGrid, 256, 0, stream>>>(qkvb, DM, 0, qkvb + S, 2 * DM, 0, pos, pos_cross,
                                         ca_scale, qb, kb);
  k_vtrans<<<vtGrid, 256, 0, stream>>>(qkvb + S, 2 * DM, DM, vtb);
  k_attn_mfma<<<attnGrid, 256, 0, stream>>>(qb, kb, vtb, ca_scale, obb);
  k_gemm<64, 0><<<dim3(DM / 64, M_TOK / 128), 256, 0, stream>>>(
      obb, wout2b, xbuf, nullptr, xbuf, M_TOK, DM, DM);

  // ---- feed-forward (fused up+SwiGLU, then down) ----
  k_rmsnorm<<<M_TOK, 256, 0, stream>>>(xbuf, ff_norm_scale, hb);
  k_ffup<<<dim3(DFF / 64, M_TOK / 128), 256, 0, stream>>>(hb, wupb, ffb);
  k_gemm<64, 0><<<dim3(DM / 64, M_TOK / 128), 256, 0, stream>>>(
      ffb, wdownb, out, nullptr, xbuf, M_TOK, DM, DFF);
}